// Round 2
// baseline (680.763 us; speedup 1.0000x reference)
//
#include <hip/hip_runtime.h>

#define N_NODES 100000
#define N_EDGES 100000
#define NNZ_C   600000
#define CAP     16          // bucket = one 64-B line; overflow list handles tail
#define OVF_MAX 4096

typedef unsigned short u16;
typedef __attribute__((ext_vector_type(8))) short short8;
typedef __attribute__((ext_vector_type(4))) float float4v;

__device__ __forceinline__ void atomAddF(float* p, float v) {
    unsafeAtomicAdd(p, v);
}

__device__ __forceinline__ u16 f2bf(float f) {     // RNE fp32 -> bf16
    union { float f; unsigned int i; } x; x.f = f;
    unsigned int r = x.i + 0x7FFFu + ((x.i >> 16) & 1u);
    return (u16)(r >> 16);
}
__device__ __forceinline__ float bf2f(u16 u) {
    union { float f; unsigned int i; } x; x.i = ((unsigned int)u) << 16; return x.f;
}

__device__ __forceinline__ short8 cvt_frag(float4 a, float4 b) {
    union { short8 s; u16 u[8]; } o;
    o.u[0] = f2bf(a.x); o.u[1] = f2bf(a.y); o.u[2] = f2bf(a.z); o.u[3] = f2bf(a.w);
    o.u[4] = f2bf(b.x); o.u[5] = f2bf(b.y); o.u[6] = f2bf(b.z); o.u[7] = f2bf(b.w);
    return o.s;
}

// relu(z*A + C) per element; A/C indexed by the fragment's k offset
__device__ __forceinline__ short8 bn_frag(short8 raw, float4 A0, float4 A1,
                                          float4 C0, float4 C1) {
    union { short8 s; u16 u[8]; } in; in.s = raw;
    union { short8 s; u16 u[8]; } o;
    o.u[0] = f2bf(fmaxf(bf2f(in.u[0]) * A0.x + C0.x, 0.0f));
    o.u[1] = f2bf(fmaxf(bf2f(in.u[1]) * A0.y + C0.y, 0.0f));
    o.u[2] = f2bf(fmaxf(bf2f(in.u[2]) * A0.z + C0.z, 0.0f));
    o.u[3] = f2bf(fmaxf(bf2f(in.u[3]) * A0.w + C0.w, 0.0f));
    o.u[4] = f2bf(fmaxf(bf2f(in.u[4]) * A1.x + C1.x, 0.0f));
    o.u[5] = f2bf(fmaxf(bf2f(in.u[5]) * A1.y + C1.y, 0.0f));
    o.u[6] = f2bf(fmaxf(bf2f(in.u[6]) * A1.z + C1.z, 0.0f));
    o.u[7] = f2bf(fmaxf(bf2f(in.u[7]) * A1.w + C1.w, 0.0f));
    return o.s;
}

// ---------------- weights: fp32 -> bf16, pre-swizzled to the LDS image ------
// Image per 128-k chunk: img[n*128 + rot(k,n)] with rot = ((k/8 + n)&15)*8 + k%8.
// GEMM staging then becomes a straight 32 KB copy (no bit-twiddling per block).
// Also zeroes cb/cd/overflow counters (was a separate hipMemsetAsync).
__global__ __launch_bounds__(256) void convert_w(
    const float* __restrict__ W1, const float* __restrict__ W2,
    const float* __restrict__ W3, u16* __restrict__ W1b,
    u16* __restrict__ W2b, u16* __restrict__ W3b, int* __restrict__ zeroMe)
{
    int i = blockIdx.x * 256 + threadIdx.x;   // 65536 total
    for (int z = i; z < 200002; z += 65536) zeroMe[z] = 0;   // cb+cd+ovf counters
    const float* src; u16* dst; int idx;
    if      (i < 32768) { src = W1; dst = W1b; idx = i; }
    else if (i < 49152) { src = W2; dst = W2b; idx = i - 32768; }
    else                { src = W3; dst = W3b; idx = i - 49152; }
    int k = idx >> 7, n = idx & 127;
    int chunk = k >> 7, kl = k & 127;
    int kb = kl >> 3, kin = kl & 7;
    dst[chunk * 16384 + n * 128 + (((kb + n) & 15) << 3) + kin] = f2bf(src[idx]);
}

// ---------------- bf16 MFMA GEMM with fused A-path preprocessing ------------
// AMODE 1: A is fp32, convert in-register (GEMM0).
// AMODE 2: A is bf16 pre-BN z; apply relu(z*As+Cs), As/Cs from raw moments.
// DOFILL : interleave the degree-count + bucket-fill scatter (transaction-
//          bound, ~0% VALU/MFMA/LDS) with the MFMA work. Each thread owns 3
//          nnz pairs; atomicAdds issue before staging, dependent atomicExch
//          after the first barrier so the GEMM hides the atomic latency and
//          the fused dispatch ~= max(fill, gemm) instead of their sum.
template<int KDIM, int AMODE, int DOFILL>
__global__ __launch_bounds__(256) void gemm_mfma(
    const void* __restrict__ Aptr, const u16* __restrict__ Wb,
    u16* __restrict__ C, int M,
    const float* __restrict__ gsum, const float* __restrict__ gsq,
    const float* __restrict__ gam, const float* __restrict__ bet, float invM,
    const int* __restrict__ fnidx, const int* __restrict__ feidx,
    int* __restrict__ cbp, int* __restrict__ cdp,
    int* __restrict__ colBp, int* __restrict__ colDp,
    uint2* __restrict__ ovfBp, uint2* __restrict__ ovfDp,
    int* __restrict__ ovfCBp, int* __restrict__ ovfCDp, int nnz)
{
    __shared__ __attribute__((aligned(16))) u16 Wt[128 * 128];   // 32 KB
    __shared__ __attribute__((aligned(16))) u16 tb[4][16][136];  // 17 KB
    __shared__ __attribute__((aligned(16))) float As[128];
    __shared__ __attribute__((aligned(16))) float Cs[128];
    const int tid = threadIdx.x;

    // ---- fused fill: load pairs, issue counter atomics (returns used later)
    int fN[3], fE[3], pB[3], pD[3];
    bool fv[3] = { false, false, false };
    if (DOFILL) {
        int base = blockIdx.x * 768 + tid;
#pragma unroll
        for (int u = 0; u < 3; u++) {
            int i = base + u * 256;
            if (i < nnz) { fv[u] = true; fN[u] = fnidx[i]; fE[u] = feidx[i]; }
        }
#pragma unroll
        for (int u = 0; u < 3; u++)
            if (fv[u]) {
                pB[u] = atomicAdd(&cbp[fE[u]], 1);
                pD[u] = atomicAdd(&cdp[fN[u]], 1);
            }
    }

    if (AMODE == 2 && tid < 128) {
        float s1 = gsum[tid] * invM;
        float var = gsq[tid] * invM - s1 * s1;
        if (var < 0.0f) var = 0.0f;
        float sc = gam[tid] * rsqrtf(var + 1e-5f);
        As[tid] = sc;
        Cs[tid] = bet[tid] - s1 * sc;   // conv bias cancels under BN
    }
    const int wave = tid >> 6, lane = tid & 63;
    const int l16 = lane & 15, quad = lane >> 4;
    const int rowt = blockIdx.x * 128 + wave * 32;
    const int r0 = rowt + l16, r1 = rowt + 16 + l16;
    const bool v0 = r0 < M, v1 = r1 < M;
    const u16*   Ab = (const u16*)Aptr;
    const float* Af = (const float*)Aptr;
    const size_t rb0 = (size_t)(v0 ? r0 : 0) * KDIM + quad * 8;
    const size_t rb1 = (size_t)(v1 ? r1 : 0) * KDIM + quad * 8;

    float4v acc[2][8];
#pragma unroll
    for (int g = 0; g < 2; g++)
#pragma unroll
        for (int c = 0; c < 8; c++) acc[g][c] = (float4v)0.0f;

    for (int kc = 0; kc < KDIM; kc += 128) {
        if (kc) __syncthreads();
        {
            const uint4* Wsrc = (const uint4*)Wb + (kc >> 7) * 2048;
            uint4* Wdst = (uint4*)Wt;
            for (int i = tid; i < 2048; i += 256) Wdst[i] = Wsrc[i];
        }
        __syncthreads();
        // ---- fused fill: dependent bucket stores, fire-and-forget; they
        // drain under the MFMA loop / later barriers.
        if (DOFILL && kc == 0) {
#pragma unroll
            for (int u = 0; u < 3; u++)
                if (fv[u]) {
                    if (pB[u] < CAP) atomicExch(&colBp[(fE[u] << 4) + pB[u]], fN[u]);
                    else { int o = atomicAdd(ovfCBp, 1); if (o < OVF_MAX) ovfBp[o] = make_uint2((unsigned)fE[u], (unsigned)fN[u]); }
                    if (pD[u] < CAP) atomicExch(&colDp[(fN[u] << 4) + pD[u]], fE[u]);
                    else { int o = atomicAdd(ovfCDp, 1); if (o < OVF_MAX) ovfDp[o] = make_uint2((unsigned)fN[u], (unsigned)fE[u]); }
                }
        }
        for (int k0 = 0; k0 < 128; k0 += 32) {
            short8 af0, af1;
            if (AMODE == 1) {
                af0 = cvt_frag(*(const float4*)(Af + rb0 + kc + k0),
                               *(const float4*)(Af + rb0 + kc + k0 + 4));
                af1 = cvt_frag(*(const float4*)(Af + rb1 + kc + k0),
                               *(const float4*)(Af + rb1 + kc + k0 + 4));
            } else {
                int kb4 = k0 + quad * 8;
                float4 A0 = *(const float4*)&As[kb4], A1 = *(const float4*)&As[kb4 + 4];
                float4 C0 = *(const float4*)&Cs[kb4], C1 = *(const float4*)&Cs[kb4 + 4];
                af0 = bn_frag(*(const short8*)(Ab + rb0 + k0), A0, A1, C0, C1);
                af1 = bn_frag(*(const short8*)(Ab + rb1 + k0), A0, A1, C0, C1);
            }
            if (!v0) af0 = (short8)(short)0;
            if (!v1) af1 = (short8)(short)0;
            const int kb = (k0 >> 3) + quad;
#pragma unroll
            for (int c = 0; c < 8; c++) {
                const int n = c * 16 + l16;
                short8 bf = *(const short8*)&Wt[n * 128 + (((kb + n) & 15) << 3)];
                acc[0][c] = __builtin_amdgcn_mfma_f32_16x16x32_bf16(af0, bf, acc[0][c], 0, 0, 0);
                acc[1][c] = __builtin_amdgcn_mfma_f32_16x16x32_bf16(af1, bf, acc[1][c], 0, 0, 0);
            }
        }
    }
#pragma unroll
    for (int g = 0; g < 2; g++) {
#pragma unroll
        for (int c = 0; c < 8; c++)
#pragma unroll
            for (int r = 0; r < 4; r++)
                tb[wave][quad * 4 + r][c * 16 + l16] = f2bf(acc[g][c][r]);
        asm volatile("s_waitcnt lgkmcnt(0)" ::: "memory");
#pragma unroll
        for (int j = 0; j < 4; j++) {
            int row_l = j * 4 + (lane >> 4);
            int row = rowt + g * 16 + row_l;
            if (row < M) {
                short8 vv = *(const short8*)&tb[wave][row_l][(lane & 15) * 8];
                *(short8*)(C + (size_t)row * 128 + (lane & 15) * 8) = vv;
            }
        }
        if (g == 0) asm volatile("s_waitcnt lgkmcnt(0)" ::: "memory");
    }
}

// ---------------- quarter-wave gather, column-phased ------------------------
// dst[r] = (1/cnt[r]) * sum src[members]; 16 lanes per row, 4 rows per wave.
// COLUMN PHASING: buckets (cnt/col) are loaded ONCE per row, then the member
// reads run in 4 phases over 64-B column slices (32 bf16 cols, 1 cache line
// per member per phase; lane = 4 B). The time-local read working set per
// phase is src[:,slice] = 6.4 MB, of which each XCD touches ~3.4 MB < its
// 4 MB L2 -> intra-phase repeat reads (avg row reuse ~6x) hit L2 instead of
// re-crossing the fabric. Worst case byte-neutral: total lines touched are
// identical to the unphased gather. Member groups of 4 use clamp-and-mask
// (clamped lanes re-read the last member's line; TA dedups same-line lanes).
// STATS: per-lane raw moments (2 cols x 4 phases) -> LDS -> one flush/block.
template<int STATS>
__global__ __launch_bounds__(256) void gather_q(
    const u16* __restrict__ src, const int* __restrict__ cnt,
    const int* __restrict__ col, u16* __restrict__ dst,
    float* __restrict__ stat, float* __restrict__ zp,
    const uint2* __restrict__ ovf, const int* __restrict__ ovfCnt, int nrows)
{
    if (zp && blockIdx.x == 0) zp[threadIdx.x] = 0.0f;
    const int tid  = threadIdx.x;
    const int lane = tid & 63;
    const int ql   = lane & 15;       // lane within quarter
    const int qid  = tid >> 4;        // quarter id within block, 0..15
    const int bsel = lane & 48;       // shfl base for this quarter
    float s1[8] = {0,0,0,0,0,0,0,0};  // [phase][2 cols]
    float s2[8] = {0,0,0,0,0,0,0,0};

    for (int rr = blockIdx.x * 16; rr < nrows; rr += gridDim.x * 16) {
        int r = rr + qid;
        if (r < nrows) {
            int c = cnt[r];                  // block-coalesced (16 consecutive)
            int m = col[(r << 4) + ql];      // one line per row, loaded once
            int cc = (c > CAP) ? CAP : c;
            int cl = cc - 1;
            float w = (c > 0) ? 1.0f / (float)c : 0.0f;
            int nov = 0;
            if (c > CAP) { nov = *ovfCnt; if (nov > OVF_MAX) nov = OVF_MAX; }
#pragma unroll
            for (int p = 0; p < 4; p++) {
                const u16* sp = src + p * 32 + ql * 2;   // lane's 2 cols in phase
                float a0 = 0.0f, a1 = 0.0f;
                for (int j = 0; j < cc; j += 4) {
                    int i1 = (j + 1 > cl) ? cl : j + 1;
                    int i2 = (j + 2 > cl) ? cl : j + 2;
                    int i3 = (j + 3 > cl) ? cl : j + 3;
                    int t0 = __shfl(m, bsel | j);
                    int t1 = __shfl(m, bsel | i1);
                    int t2 = __shfl(m, bsel | i2);
                    int t3 = __shfl(m, bsel | i3);
                    unsigned va = *(const unsigned*)(sp + (size_t)t0 * 128);
                    unsigned vb = *(const unsigned*)(sp + (size_t)t1 * 128);
                    unsigned vc = *(const unsigned*)(sp + (size_t)t2 * 128);
                    unsigned vd = *(const unsigned*)(sp + (size_t)t3 * 128);
                    if (j + 1 > cl) vb = 0u;
                    if (j + 2 > cl) vc = 0u;
                    if (j + 3 > cl) vd = 0u;
                    a0 += bf2f((u16)(va & 0xFFFF)) + bf2f((u16)(vb & 0xFFFF))
                        + bf2f((u16)(vc & 0xFFFF)) + bf2f((u16)(vd & 0xFFFF));
                    a1 += bf2f((u16)(va >> 16)) + bf2f((u16)(vb >> 16))
                        + bf2f((u16)(vc >> 16)) + bf2f((u16)(vd >> 16));
                }
                if (c > CAP) {               // rare: scan overflow list
                    for (int i4 = 0; i4 < nov; i4++) {
                        uint2 pp = ovf[i4];
                        if ((int)pp.x == r) {
                            unsigned va = *(const unsigned*)(sp + (size_t)pp.y * 128);
                            a0 += bf2f((u16)(va & 0xFFFF));
                            a1 += bf2f((u16)(va >> 16));
                        }
                    }
                }
                a0 *= w; a1 *= w;
                *(unsigned*)(dst + (size_t)r * 128 + p * 32 + ql * 2) =
                    (unsigned)f2bf(a0) | ((unsigned)f2bf(a1) << 16);
                if (STATS) {
                    s1[2 * p]     += a0;      s1[2 * p + 1] += a1;
                    s2[2 * p]     += a0 * a0; s2[2 * p + 1] += a1 * a1;
                }
            }
        }
    }
    if (STATS) {
        __shared__ float redS[16][128];
        __shared__ float redQ[16][128];
#pragma unroll
        for (int p = 0; p < 4; p++) {
            redS[qid][p * 32 + ql * 2]     = s1[2 * p];
            redS[qid][p * 32 + ql * 2 + 1] = s1[2 * p + 1];
            redQ[qid][p * 32 + ql * 2]     = s2[2 * p];
            redQ[qid][p * 32 + ql * 2 + 1] = s2[2 * p + 1];
        }
        __syncthreads();
        int t = tid & 127;
        float accv = 0.0f;
        if (tid < 128) {
#pragma unroll
            for (int q = 0; q < 16; q++) accv += redS[q][t];
            atomAddF(&stat[t], accv);
        } else {
#pragma unroll
            for (int q = 0; q < 16; q++) accv += redQ[q][t];
            atomAddF(&stat[128 + t], accv);
        }
    }
}

// ---------------- MFMA classifier with fused BN on the A-path ---------------
__global__ __launch_bounds__(256) void classifier_mfma(
    const u16* __restrict__ Z, const float* __restrict__ Wc1,
    const float* __restrict__ bc1, const float* __restrict__ Wc2,
    const float* __restrict__ bc2, float* __restrict__ out, int M,
    const float* __restrict__ gsum, const float* __restrict__ gsq,
    const float* __restrict__ gam, const float* __restrict__ bet, float invM)
{
    __shared__ __attribute__((aligned(16))) u16 W1t[64 * 128];   // 16 KB
    __shared__ __attribute__((aligned(16))) u16 W2t[16 * 64];    // 2 KB
    __shared__ __attribute__((aligned(16))) u16 hs[128][72];     // 18.4 KB
    __shared__ __attribute__((aligned(16))) float As[128];
    __shared__ __attribute__((aligned(16))) float Cs[128];
    const int tid = threadIdx.x;
    if (tid < 128) {
        float s1 = gsum[tid] * invM;
        float var = gsq[tid] * invM - s1 * s1;
        if (var < 0.0f) var = 0.0f;
        float sc = gam[tid] * rsqrtf(var + 1e-5f);
        As[tid] = sc;
        Cs[tid] = bet[tid] - s1 * sc;
    }
    for (int i = tid; i < 64 * 128; i += 256) {   // i = k*64 + n
        int k = i >> 6, n = i & 63;
        int kb = k >> 3, kin = k & 7;
        W1t[n * 128 + (((kb + n) & 15) << 3) + kin] = f2bf(Wc1[i]);
    }
    for (int i = tid; i < 16 * 64; i += 256) {    // i = k*16 + n
        int k = i >> 4, n = i & 15;
        W2t[n * 64 + k] = (n < 10) ? f2bf(Wc2[k * 10 + n]) : (u16)0;
    }
    __syncthreads();

    const int wave = tid >> 6, lane = tid & 63;
    const int l16 = lane & 15, quad = lane >> 4;
    const int rowt = blockIdx.x * 128 + wave * 32;
    const int r0 = rowt + l16, r1 = rowt + 16 + l16;
    const bool v0 = r0 < M, v1 = r1 < M;
    const u16* a0p = Z + (size_t)(v0 ? r0 : 0) * 128 + quad * 8;
    const u16* a1p = Z + (size_t)(v1 ? r1 : 0) * 128 + quad * 8;

    float4v acc[2][4];
#pragma unroll
    for (int g = 0; g < 2; g++)
#pragma unroll
        for (int c = 0; c < 4; c++) acc[g][c] = (float4v)0.0f;

#pragma unroll
    for (int k0 = 0; k0 < 128; k0 += 32) {
        int kb4 = k0 + quad * 8;
        float4 A0 = *(const float4*)&As[kb4], A1 = *(const float4*)&As[kb4 + 4];
        float4 C0 = *(const float4*)&Cs[kb4], C1 = *(const float4*)&Cs[kb4 + 4];
        short8 af0 = bn_frag(*(const short8*)(a0p + k0), A0, A1, C0, C1);
        short8 af1 = bn_frag(*(const short8*)(a1p + k0), A0, A1, C0, C1);
        if (!v0) af0 = (short8)(short)0;
        if (!v1) af1 = (short8)(short)0;
        const int kb = (k0 >> 3) + quad;
#pragma unroll
        for (int c = 0; c < 4; c++) {
            const int n = c * 16 + l16;
            short8 bf = *(const short8*)&W1t[n * 128 + (((kb + n) & 15) << 3)];
            acc[0][c] = __builtin_amdgcn_mfma_f32_16x16x32_bf16(af0, bf, acc[0][c], 0, 0, 0);
            acc[1][c] = __builtin_amdgcn_mfma_f32_16x16x32_bf16(af1, bf, acc[1][c], 0, 0, 0);
        }
    }
#pragma unroll
    for (int g = 0; g < 2; g++)
#pragma unroll
        for (int c = 0; c < 4; c++) {
            float b = bc1[c * 16 + l16];
#pragma unroll
            for (int r = 0; r < 4; r++)
                hs[wave * 32 + g * 16 + quad * 4 + r][c * 16 + l16] =
                    f2bf(fmaxf(acc[g][c][r] + b, 0.0f));
        }
    asm volatile("s_waitcnt lgkmcnt(0)" ::: "memory");

    float4v a2[2];
    a2[0] = (float4v)0.0f; a2[1] = (float4v)0.0f;
#pragma unroll
    for (int k0 = 0; k0 < 64; k0 += 32) {
        short8 bf = *(const short8*)&W2t[l16 * 64 + k0 + quad * 8];
#pragma unroll
        for (int g = 0; g < 2; g++) {
            short8 af = *(const short8*)&hs[wave * 32 + g * 16 + l16][k0 + quad * 8];
            a2[g] = __builtin_amdgcn_mfma_f32_16x16x32_bf16(af, bf, a2[g], 0, 0, 0);
        }
    }
    if (l16 < 10) {
        float b2 = bc2[l16];
#pragma unroll
        for (int g = 0; g < 2; g++)
#pragma unroll
            for (int r = 0; r < 4; r++) {
                int row = rowt + g * 16 + quad * 4 + r;
                if (row < M) out[(size_t)row * 10 + l16] = a2[g][r] + b2;
            }
    }
}

// ---------------- launch ----------------------------------------------------
extern "C" void kernel_launch(void* const* d_in, const int* in_sizes, int n_in,
                              void* d_out, int out_size, void* d_ws, size_t ws_size,
                              hipStream_t stream)
{
    const int M   = N_NODES;
    const int NE  = N_EDGES;
    const int nnz = NNZ_C;

    const float* x   = (const float*)d_in[0];
    const int*  nidx = (const int*)d_in[1];
    const int*  eidx = nidx + nnz;
    const float* W1  = (const float*)d_in[2];
    const float* W2  = (const float*)d_in[4];
    const float* W3  = (const float*)d_in[6];
    const float* g1  = (const float*)d_in[8];
    const float* bt1 = (const float*)d_in[9];
    const float* g2  = (const float*)d_in[10];
    const float* bt2 = (const float*)d_in[11];
    const float* g3  = (const float*)d_in[12];
    const float* bt3 = (const float*)d_in[13];
    const float* Wc1 = (const float*)d_in[14];
    const float* bc1 = (const float*)d_in[15];
    const float* Wc2 = (const float*)d_in[16];
    const float* bc2 = (const float*)d_in[17];
    float* out = (float*)d_out;

    // ---- workspace carve-up ----
    const size_t SZH = (size_t)M * 128 * sizeof(u16);   // 25.6 MB
    char* ws = (char*)d_ws;
    u16* Y = (u16*)(ws);                     // GEMM output (bf16)
    u16* E = (u16*)(ws + SZH);               // edge features (bf16)
    u16* Z = (u16*)(ws + 2 * SZH);           // node agg, pre-BN (bf16)
    int* ib = (int*)(ws + 3 * SZH);
    int*   cb      = ib;                     // edge sizes / cursors [100000]
    int*   cd      = ib + 100000;            // node degrees / cursors
    int*   ovfCntB = ib + 200000;
    int*   ovfCntD = ib + 200001;
    int*   colB    = ib + 200016;            // 64-B aligned; [100000*16]
    int*   colD    = ib + 200016 + NE * CAP;
    uint2* ovfB    = (uint2*)(ib + 200016 + (NE + M) * CAP);
    uint2* ovfD    = ovfB + OVF_MAX;
    float* fb = (float*)(ovfD + OVF_MAX);
    float* gsum = fb;                        // [128]; gsq contiguous after
    u16* wbuf = (u16*)(fb + 256);
    u16* W1b = wbuf;                         // 2 chunks x 16384 (swizzled)
    u16* W2b = wbuf + 32768;                 // 1 chunk
    u16* W3b = wbuf + 49152;                 // 1 chunk

    const int ntiles = (M + 127) / 128;
    const float invM = 1.0f / (float)M;

    // ---- weight convert + counter zeroing (replaces the memset dispatch) ----
    convert_w<<<256, 256, 0, stream>>>(W1, W2, W3, W1b, W2b, W3b, cb);

    const float* gin[3]  = { g1, g2, g3 };
    const float* btin[3] = { bt1, bt2, bt3 };
    const u16*   Wbf[3]  = { W1b, W2b, W3b };

    for (int L = 0; L < 3; L++) {
        if (L == 0)
            // GEMM0 fused with index preprocessing: the scatter-atomic fill is
            // transaction-bound (~0% VALU, 9% HBM) and overlaps the MFMA work.
            gemm_mfma<256, 1, 1><<<ntiles, 256, 0, stream>>>(
                x, Wbf[0], Y, M, nullptr, nullptr, nullptr, nullptr, 0.0f,
                nidx, eidx, cb, cd, colB, colD, ovfB, ovfD, ovfCntB, ovfCntD, nnz);
        else
            gemm_mfma<128, 2, 0><<<ntiles, 256, 0, stream>>>(
                Z, Wbf[L], Y, M, gsum, gsum + 128, gin[L - 1], btin[L - 1], invM,
                nullptr, nullptr, nullptr, nullptr, nullptr, nullptr,
                nullptr, nullptr, nullptr, nullptr, 0);
        // edge aggregation; block 0 zeros gsum||gsq for the node pass
        gather_q<0><<<(NE + 15) / 16, 256, 0, stream>>>(
            Y, cb, colB, E, nullptr, gsum, ovfB, ovfCntB, NE);
        // node aggregation with fused raw-moment stats (2048 blocks = 8/CU)
        gather_q<1><<<2048, 256, 0, stream>>>(
            E, cd, colD, Z, gsum, nullptr, ovfD, ovfCntD, M);
    }

    classifier_mfma<<<ntiles, 256, 0, stream>>>(
        Z, Wc1, bc1, Wc2, bc2, out, M, gsum, gsum + 128, gin[2], btin[2], invM);
}

// Round 3
// 609.435 us; speedup vs baseline: 1.1170x; 1.1170x over previous
//
#include <hip/hip_runtime.h>

#define N_NODES 100000
#define N_EDGES 100000
#define NNZ_C   600000
#define CAP     16          // bucket = one 64-B line; overflow list handles tail
#define OVF_MAX 4096
#define FILLB   512         // dedicated fill blocks prepended to the gemm0 grid

typedef unsigned short u16;
typedef __attribute__((ext_vector_type(8))) short short8;
typedef __attribute__((ext_vector_type(4))) float float4v;

__device__ __forceinline__ void atomAddF(float* p, float v) {
    unsafeAtomicAdd(p, v);
}

__device__ __forceinline__ u16 f2bf(float f) {     // RNE fp32 -> bf16
    union { float f; unsigned int i; } x; x.f = f;
    unsigned int r = x.i + 0x7FFFu + ((x.i >> 16) & 1u);
    return (u16)(r >> 16);
}
__device__ __forceinline__ float bf2f(u16 u) {
    union { float f; unsigned int i; } x; x.i = ((unsigned int)u) << 16; return x.f;
}

__device__ __forceinline__ short8 cvt_frag(float4 a, float4 b) {
    union { short8 s; u16 u[8]; } o;
    o.u[0] = f2bf(a.x); o.u[1] = f2bf(a.y); o.u[2] = f2bf(a.z); o.u[3] = f2bf(a.w);
    o.u[4] = f2bf(b.x); o.u[5] = f2bf(b.y); o.u[6] = f2bf(b.z); o.u[7] = f2bf(b.w);
    return o.s;
}

// relu(z*A + C) per element; A/C indexed by the fragment's k offset
__device__ __forceinline__ short8 bn_frag(short8 raw, float4 A0, float4 A1,
                                          float4 C0, float4 C1) {
    union { short8 s; u16 u[8]; } in; in.s = raw;
    union { short8 s; u16 u[8]; } o;
    o.u[0] = f2bf(fmaxf(bf2f(in.u[0]) * A0.x + C0.x, 0.0f));
    o.u[1] = f2bf(fmaxf(bf2f(in.u[1]) * A0.y + C0.y, 0.0f));
    o.u[2] = f2bf(fmaxf(bf2f(in.u[2]) * A0.z + C0.z, 0.0f));
    o.u[3] = f2bf(fmaxf(bf2f(in.u[3]) * A0.w + C0.w, 0.0f));
    o.u[4] = f2bf(fmaxf(bf2f(in.u[4]) * A1.x + C1.x, 0.0f));
    o.u[5] = f2bf(fmaxf(bf2f(in.u[5]) * A1.y + C1.y, 0.0f));
    o.u[6] = f2bf(fmaxf(bf2f(in.u[6]) * A1.z + C1.z, 0.0f));
    o.u[7] = f2bf(fmaxf(bf2f(in.u[7]) * A1.w + C1.w, 0.0f));
    return o.s;
}

// ---------------- weights: fp32 -> bf16, pre-swizzled to the LDS image ------
// Image per 128-k chunk: img[n*128 + rot(k,n)] with rot = ((k/8 + n)&15)*8 + k%8.
// GEMM staging then becomes a straight 32 KB copy (no bit-twiddling per block).
// Also zeroes cb/cd/overflow counters (was a separate hipMemsetAsync).
__global__ __launch_bounds__(256) void convert_w(
    const float* __restrict__ W1, const float* __restrict__ W2,
    const float* __restrict__ W3, u16* __restrict__ W1b,
    u16* __restrict__ W2b, u16* __restrict__ W3b, int* __restrict__ zeroMe)
{
    int i = blockIdx.x * 256 + threadIdx.x;   // 65536 total
    for (int z = i; z < 200002; z += 65536) zeroMe[z] = 0;   // cb+cd+ovf counters
    const float* src; u16* dst; int idx;
    if      (i < 32768) { src = W1; dst = W1b; idx = i; }
    else if (i < 49152) { src = W2; dst = W2b; idx = i - 32768; }
    else                { src = W3; dst = W3b; idx = i - 49152; }
    int k = idx >> 7, n = idx & 127;
    int chunk = k >> 7, kl = k & 127;
    int kb = kl >> 3, kin = kl & 7;
    dst[chunk * 16384 + n * 128 + (((kb + n) & 15) << 3) + kin] = f2bf(src[idx]);
}

// ---------------- bf16 MFMA GEMM, optionally sharing its grid with fill -----
// AMODE 1: A is fp32, convert in-register (GEMM0).
// AMODE 2: A is bf16 pre-BN z; apply relu(z*As+Cs), As/Cs from raw moments.
// DOFILL : blocks [0, FILLB) are DEDICATED fill blocks (no LDS, 4 waves) that
//          run the degree-count + bucket-fill scatter concurrently with the
//          gemm blocks [FILLB, FILLB+ntiles). Role split by blockIdx — NOT
//          thread interleaving: vmcnt is one in-order counter per wave, so a
//          wave that issues fill atomics serializes its own gemm loads behind
//          the chip-wide atomic drain (the round-1 fusion saved ~0). Separate
//          waves give dispatch ~= max(fill, gemm) with no vmcnt coupling.
//          Fill blocks use no barriers and exit early; gemm blocks are
//          LDS-limited to 3/CU (12 waves), fill adds ~8 waves/CU -> fits 32.
template<int KDIM, int AMODE, int DOFILL>
__global__ __launch_bounds__(256) void gemm_mfma(
    const void* __restrict__ Aptr, const u16* __restrict__ Wb,
    u16* __restrict__ C, int M,
    const float* __restrict__ gsum, const float* __restrict__ gsq,
    const float* __restrict__ gam, const float* __restrict__ bet, float invM,
    const int* __restrict__ fnidx, const int* __restrict__ feidx,
    int* __restrict__ cbp, int* __restrict__ cdp,
    int* __restrict__ colBp, int* __restrict__ colDp,
    uint2* __restrict__ ovfBp, uint2* __restrict__ ovfDp,
    int* __restrict__ ovfCBp, int* __restrict__ ovfCDp, int nnz)
{
    const int tid = threadIdx.x;

    if (DOFILL && blockIdx.x < FILLB) {
        // ---- fill role: 131072 threads x up-to-5 pairs, batch-issued ----
        int gt = blockIdx.x * 256 + tid;
        int fN[5], fE[5], pB[5], pD[5];
        bool fv[5];
#pragma unroll
        for (int u = 0; u < 5; u++) {
            int i = gt + u * (FILLB * 256);
            fv[u] = (i < nnz);
            if (fv[u]) { fN[u] = fnidx[i]; fE[u] = feidx[i]; }
        }
#pragma unroll
        for (int u = 0; u < 5; u++)
            if (fv[u]) {
                pB[u] = atomicAdd(&cbp[fE[u]], 1);
                pD[u] = atomicAdd(&cdp[fN[u]], 1);
            }
#pragma unroll
        for (int u = 0; u < 5; u++)
            if (fv[u]) {
                if (pB[u] < CAP) atomicExch(&colBp[(fE[u] << 4) + pB[u]], fN[u]);
                else { int o = atomicAdd(ovfCBp, 1); if (o < OVF_MAX) ovfBp[o] = make_uint2((unsigned)fE[u], (unsigned)fN[u]); }
                if (pD[u] < CAP) atomicExch(&colDp[(fN[u] << 4) + pD[u]], fE[u]);
                else { int o = atomicAdd(ovfCDp, 1); if (o < OVF_MAX) ovfDp[o] = make_uint2((unsigned)fN[u], (unsigned)fE[u]); }
            }
        return;
    }
    const int bx = DOFILL ? ((int)blockIdx.x - FILLB) : (int)blockIdx.x;

    __shared__ __attribute__((aligned(16))) u16 Wt[128 * 128];   // 32 KB
    __shared__ __attribute__((aligned(16))) u16 tb[4][16][136];  // 17 KB
    __shared__ __attribute__((aligned(16))) float As[128];
    __shared__ __attribute__((aligned(16))) float Cs[128];

    if (AMODE == 2 && tid < 128) {
        float s1 = gsum[tid] * invM;
        float var = gsq[tid] * invM - s1 * s1;
        if (var < 0.0f) var = 0.0f;
        float sc = gam[tid] * rsqrtf(var + 1e-5f);
        As[tid] = sc;
        Cs[tid] = bet[tid] - s1 * sc;   // conv bias cancels under BN
    }
    const int wave = tid >> 6, lane = tid & 63;
    const int l16 = lane & 15, quad = lane >> 4;
    const int rowt = bx * 128 + wave * 32;
    const int r0 = rowt + l16, r1 = rowt + 16 + l16;
    const bool v0 = r0 < M, v1 = r1 < M;
    const u16*   Ab = (const u16*)Aptr;
    const float* Af = (const float*)Aptr;
    const size_t rb0 = (size_t)(v0 ? r0 : 0) * KDIM + quad * 8;
    const size_t rb1 = (size_t)(v1 ? r1 : 0) * KDIM + quad * 8;

    float4v acc[2][8];
#pragma unroll
    for (int g = 0; g < 2; g++)
#pragma unroll
        for (int c = 0; c < 8; c++) acc[g][c] = (float4v)0.0f;

    for (int kc = 0; kc < KDIM; kc += 128) {
        if (kc) __syncthreads();
        {
            const uint4* Wsrc = (const uint4*)Wb + (kc >> 7) * 2048;
            uint4* Wdst = (uint4*)Wt;
            for (int i = tid; i < 2048; i += 256) Wdst[i] = Wsrc[i];
        }
        __syncthreads();
        for (int k0 = 0; k0 < 128; k0 += 32) {
            short8 af0, af1;
            if (AMODE == 1) {
                af0 = cvt_frag(*(const float4*)(Af + rb0 + kc + k0),
                               *(const float4*)(Af + rb0 + kc + k0 + 4));
                af1 = cvt_frag(*(const float4*)(Af + rb1 + kc + k0),
                               *(const float4*)(Af + rb1 + kc + k0 + 4));
            } else {
                int kb4 = k0 + quad * 8;
                float4 A0 = *(const float4*)&As[kb4], A1 = *(const float4*)&As[kb4 + 4];
                float4 C0 = *(const float4*)&Cs[kb4], C1 = *(const float4*)&Cs[kb4 + 4];
                af0 = bn_frag(*(const short8*)(Ab + rb0 + k0), A0, A1, C0, C1);
                af1 = bn_frag(*(const short8*)(Ab + rb1 + k0), A0, A1, C0, C1);
            }
            if (!v0) af0 = (short8)(short)0;
            if (!v1) af1 = (short8)(short)0;
            const int kb = (k0 >> 3) + quad;
#pragma unroll
            for (int c = 0; c < 8; c++) {
                const int n = c * 16 + l16;
                short8 bf = *(const short8*)&Wt[n * 128 + (((kb + n) & 15) << 3)];
                acc[0][c] = __builtin_amdgcn_mfma_f32_16x16x32_bf16(af0, bf, acc[0][c], 0, 0, 0);
                acc[1][c] = __builtin_amdgcn_mfma_f32_16x16x32_bf16(af1, bf, acc[1][c], 0, 0, 0);
            }
        }
    }
#pragma unroll
    for (int g = 0; g < 2; g++) {
#pragma unroll
        for (int c = 0; c < 8; c++)
#pragma unroll
            for (int r = 0; r < 4; r++)
                tb[wave][quad * 4 + r][c * 16 + l16] = f2bf(acc[g][c][r]);
        asm volatile("s_waitcnt lgkmcnt(0)" ::: "memory");
#pragma unroll
        for (int j = 0; j < 4; j++) {
            int row_l = j * 4 + (lane >> 4);
            int row = rowt + g * 16 + row_l;
            if (row < M) {
                short8 vv = *(const short8*)&tb[wave][row_l][(lane & 15) * 8];
                *(short8*)(C + (size_t)row * 128 + (lane & 15) * 8) = vv;
            }
        }
        if (g == 0) asm volatile("s_waitcnt lgkmcnt(0)" ::: "memory");
    }
}

// ---------------- quarter-wave gather: 16 lanes/row, uint4 (8 bf16)/lane ----
// dst[r] = (1/cnt[r]) * sum src[members]; 4 rows per wave, 16 B/lane loads.
// (Round-2 column phasing REVERTED: per-phase slices thrash L2 anyway — every
// XCD reads the full slice, 6.4 MB > 4 MB — and 64-B requests break 128-B
// line granularity while 4x-ing instruction count. Full-row reads touch the
// minimum set of lines.)
// cnt and col load concurrently (col read unconditionally; garbage lanes are
// never shfl-selected); the member loop always issues a full clamp-and-mask
// group of 4 (clamped lanes re-read the last member's line — TA dedups
// same-line lanes — and are masked to 0 before accumulation).
// STATS: per-lane 8-column raw moments -> LDS -> one 256-atomic flush/block.
template<int STATS>
__global__ __launch_bounds__(256) void gather_q(
    const u16* __restrict__ src, const int* __restrict__ cnt,
    const int* __restrict__ col, u16* __restrict__ dst,
    float* __restrict__ stat, float* __restrict__ zp,
    const uint2* __restrict__ ovf, const int* __restrict__ ovfCnt, int nrows)
{
    if (zp && blockIdx.x == 0) zp[threadIdx.x] = 0.0f;
    const int tid  = threadIdx.x;
    const int lane = tid & 63;
    const int ql   = lane & 15;       // lane within quarter
    const int qid  = tid >> 4;        // quarter id within block, 0..15
    const int bsel = lane & 48;       // shfl base for this quarter
    const u16* srcq = src + ql * 8;   // this lane's 8 columns
    float s1[8] = {0,0,0,0,0,0,0,0};
    float s2[8] = {0,0,0,0,0,0,0,0};

    for (int rr = blockIdx.x * 16; rr < nrows; rr += gridDim.x * 16) {
        int r = rr + qid;
        if (r < nrows) {
            int c = cnt[r];
            int m = col[(r << 4) + ql];      // issues concurrently with cnt
            int cc = (c > CAP) ? CAP : c;
            float a[8] = {0,0,0,0,0,0,0,0};
            int cl = cc - 1;
            for (int j = 0; j < cc; j += 4) {
                int i1 = (j + 1 > cl) ? cl : j + 1;
                int i2 = (j + 2 > cl) ? cl : j + 2;
                int i3 = (j + 3 > cl) ? cl : j + 3;
                int t0 = __shfl(m, bsel | j);
                int t1 = __shfl(m, bsel | i1);
                int t2 = __shfl(m, bsel | i2);
                int t3 = __shfl(m, bsel | i3);
                uint4 va = *(const uint4*)(srcq + (size_t)t0 * 128);
                uint4 vb = *(const uint4*)(srcq + (size_t)t1 * 128);
                uint4 vc = *(const uint4*)(srcq + (size_t)t2 * 128);
                uint4 vd = *(const uint4*)(srcq + (size_t)t3 * 128);
                if (j + 1 > cl) vb = make_uint4(0, 0, 0, 0);
                if (j + 2 > cl) vc = make_uint4(0, 0, 0, 0);
                if (j + 3 > cl) vd = make_uint4(0, 0, 0, 0);
                a[0] += bf2f((u16)(va.x & 0xFFFF)) + bf2f((u16)(vb.x & 0xFFFF))
                      + bf2f((u16)(vc.x & 0xFFFF)) + bf2f((u16)(vd.x & 0xFFFF));
                a[1] += bf2f((u16)(va.x >> 16)) + bf2f((u16)(vb.x >> 16))
                      + bf2f((u16)(vc.x >> 16)) + bf2f((u16)(vd.x >> 16));
                a[2] += bf2f((u16)(va.y & 0xFFFF)) + bf2f((u16)(vb.y & 0xFFFF))
                      + bf2f((u16)(vc.y & 0xFFFF)) + bf2f((u16)(vd.y & 0xFFFF));
                a[3] += bf2f((u16)(va.y >> 16)) + bf2f((u16)(vb.y >> 16))
                      + bf2f((u16)(vc.y >> 16)) + bf2f((u16)(vd.y >> 16));
                a[4] += bf2f((u16)(va.z & 0xFFFF)) + bf2f((u16)(vb.z & 0xFFFF))
                      + bf2f((u16)(vc.z & 0xFFFF)) + bf2f((u16)(vd.z & 0xFFFF));
                a[5] += bf2f((u16)(va.z >> 16)) + bf2f((u16)(vb.z >> 16))
                      + bf2f((u16)(vc.z >> 16)) + bf2f((u16)(vd.z >> 16));
                a[6] += bf2f((u16)(va.w & 0xFFFF)) + bf2f((u16)(vb.w & 0xFFFF))
                      + bf2f((u16)(vc.w & 0xFFFF)) + bf2f((u16)(vd.w & 0xFFFF));
                a[7] += bf2f((u16)(va.w >> 16)) + bf2f((u16)(vb.w >> 16))
                      + bf2f((u16)(vc.w >> 16)) + bf2f((u16)(vd.w >> 16));
            }
            if (c > CAP) {                 // rare: scan overflow list
                int nov = *ovfCnt; if (nov > OVF_MAX) nov = OVF_MAX;
                for (int i2 = 0; i2 < nov; i2++) {
                    uint2 p = ovf[i2];
                    if ((int)p.x == r) {
                        uint4 va = *(const uint4*)(srcq + (size_t)p.y * 128);
                        a[0] += bf2f((u16)(va.x & 0xFFFF)); a[1] += bf2f((u16)(va.x >> 16));
                        a[2] += bf2f((u16)(va.y & 0xFFFF)); a[3] += bf2f((u16)(va.y >> 16));
                        a[4] += bf2f((u16)(va.z & 0xFFFF)); a[5] += bf2f((u16)(va.z >> 16));
                        a[6] += bf2f((u16)(va.w & 0xFFFF)); a[7] += bf2f((u16)(va.w >> 16));
                    }
                }
            }
            float w = (c > 0) ? 1.0f / (float)c : 0.0f;
#pragma unroll
            for (int k = 0; k < 8; k++) a[k] *= w;
            uint4 o;
            o.x = (unsigned)f2bf(a[0]) | ((unsigned)f2bf(a[1]) << 16);
            o.y = (unsigned)f2bf(a[2]) | ((unsigned)f2bf(a[3]) << 16);
            o.z = (unsigned)f2bf(a[4]) | ((unsigned)f2bf(a[5]) << 16);
            o.w = (unsigned)f2bf(a[6]) | ((unsigned)f2bf(a[7]) << 16);
            *(uint4*)(dst + (size_t)r * 128 + ql * 8) = o;
            if (STATS) {
#pragma unroll
                for (int k = 0; k < 8; k++) { s1[k] += a[k]; s2[k] += a[k] * a[k]; }
            }
        }
    }
    if (STATS) {
        __shared__ float redS[16][128];
        __shared__ float redQ[16][128];
#pragma unroll
        for (int k = 0; k < 8; k++) {
            redS[qid][ql * 8 + k] = s1[k];
            redQ[qid][ql * 8 + k] = s2[k];
        }
        __syncthreads();
        int t = tid & 127;
        float accv = 0.0f;
        if (tid < 128) {
#pragma unroll
            for (int q = 0; q < 16; q++) accv += redS[q][t];
            atomAddF(&stat[t], accv);
        } else {
#pragma unroll
            for (int q = 0; q < 16; q++) accv += redQ[q][t];
            atomAddF(&stat[128 + t], accv);
        }
    }
}

// ---------------- MFMA classifier with fused BN on the A-path ---------------
__global__ __launch_bounds__(256) void classifier_mfma(
    const u16* __restrict__ Z, const float* __restrict__ Wc1,
    const float* __restrict__ bc1, const float* __restrict__ Wc2,
    const float* __restrict__ bc2, float* __restrict__ out, int M,
    const float* __restrict__ gsum, const float* __restrict__ gsq,
    const float* __restrict__ gam, const float* __restrict__ bet, float invM)
{
    __shared__ __attribute__((aligned(16))) u16 W1t[64 * 128];   // 16 KB
    __shared__ __attribute__((aligned(16))) u16 W2t[16 * 64];    // 2 KB
    __shared__ __attribute__((aligned(16))) u16 hs[128][72];     // 18.4 KB
    __shared__ __attribute__((aligned(16))) float As[128];
    __shared__ __attribute__((aligned(16))) float Cs[128];
    const int tid = threadIdx.x;
    if (tid < 128) {
        float s1 = gsum[tid] * invM;
        float var = gsq[tid] * invM - s1 * s1;
        if (var < 0.0f) var = 0.0f;
        float sc = gam[tid] * rsqrtf(var + 1e-5f);
        As[tid] = sc;
        Cs[tid] = bet[tid] - s1 * sc;
    }
    for (int i = tid; i < 64 * 128; i += 256) {   // i = k*64 + n
        int k = i >> 6, n = i & 63;
        int kb = k >> 3, kin = k & 7;
        W1t[n * 128 + (((kb + n) & 15) << 3) + kin] = f2bf(Wc1[i]);
    }
    for (int i = tid; i < 16 * 64; i += 256) {    // i = k*16 + n
        int k = i >> 4, n = i & 15;
        W2t[n * 64 + k] = (n < 10) ? f2bf(Wc2[k * 10 + n]) : (u16)0;
    }
    __syncthreads();

    const int wave = tid >> 6, lane = tid & 63;
    const int l16 = lane & 15, quad = lane >> 4;
    const int rowt = blockIdx.x * 128 + wave * 32;
    const int r0 = rowt + l16, r1 = rowt + 16 + l16;
    const bool v0 = r0 < M, v1 = r1 < M;
    const u16* a0p = Z + (size_t)(v0 ? r0 : 0) * 128 + quad * 8;
    const u16* a1p = Z + (size_t)(v1 ? r1 : 0) * 128 + quad * 8;

    float4v acc[2][4];
#pragma unroll
    for (int g = 0; g < 2; g++)
#pragma unroll
        for (int c = 0; c < 4; c++) acc[g][c] = (float4v)0.0f;

#pragma unroll
    for (int k0 = 0; k0 < 128; k0 += 32) {
        int kb4 = k0 + quad * 8;
        float4 A0 = *(const float4*)&As[kb4], A1 = *(const float4*)&As[kb4 + 4];
        float4 C0 = *(const float4*)&Cs[kb4], C1 = *(const float4*)&Cs[kb4 + 4];
        short8 af0 = bn_frag(*(const short8*)(a0p + k0), A0, A1, C0, C1);
        short8 af1 = bn_frag(*(const short8*)(a1p + k0), A0, A1, C0, C1);
        if (!v0) af0 = (short8)(short)0;
        if (!v1) af1 = (short8)(short)0;
        const int kb = (k0 >> 3) + quad;
#pragma unroll
        for (int c = 0; c < 4; c++) {
            const int n = c * 16 + l16;
            short8 bf = *(const short8*)&W1t[n * 128 + (((kb + n) & 15) << 3)];
            acc[0][c] = __builtin_amdgcn_mfma_f32_16x16x32_bf16(af0, bf, acc[0][c], 0, 0, 0);
            acc[1][c] = __builtin_amdgcn_mfma_f32_16x16x32_bf16(af1, bf, acc[1][c], 0, 0, 0);
        }
    }
#pragma unroll
    for (int g = 0; g < 2; g++)
#pragma unroll
        for (int c = 0; c < 4; c++) {
            float b = bc1[c * 16 + l16];
#pragma unroll
            for (int r = 0; r < 4; r++)
                hs[wave * 32 + g * 16 + quad * 4 + r][c * 16 + l16] =
                    f2bf(fmaxf(acc[g][c][r] + b, 0.0f));
        }
    asm volatile("s_waitcnt lgkmcnt(0)" ::: "memory");

    float4v a2[2];
    a2[0] = (float4v)0.0f; a2[1] = (float4v)0.0f;
#pragma unroll
    for (int k0 = 0; k0 < 64; k0 += 32) {
        short8 bf = *(const short8*)&W2t[l16 * 64 + k0 + quad * 8];
#pragma unroll
        for (int g = 0; g < 2; g++) {
            short8 af = *(const short8*)&hs[wave * 32 + g * 16 + l16][k0 + quad * 8];
            a2[g] = __builtin_amdgcn_mfma_f32_16x16x32_bf16(af, bf, a2[g], 0, 0, 0);
        }
    }
    if (l16 < 10) {
        float b2 = bc2[l16];
#pragma unroll
        for (int g = 0; g < 2; g++)
#pragma unroll
            for (int r = 0; r < 4; r++) {
                int row = rowt + g * 16 + quad * 4 + r;
                if (row < M) out[(size_t)row * 10 + l16] = a2[g][r] + b2;
            }
    }
}

// ---------------- launch ----------------------------------------------------
extern "C" void kernel_launch(void* const* d_in, const int* in_sizes, int n_in,
                              void* d_out, int out_size, void* d_ws, size_t ws_size,
                              hipStream_t stream)
{
    const int M   = N_NODES;
    const int NE  = N_EDGES;
    const int nnz = NNZ_C;

    const float* x   = (const float*)d_in[0];
    const int*  nidx = (const int*)d_in[1];
    const int*  eidx = nidx + nnz;
    const float* W1  = (const float*)d_in[2];
    const float* W2  = (const float*)d_in[4];
    const float* W3  = (const float*)d_in[6];
    const float* g1  = (const float*)d_in[8];
    const float* bt1 = (const float*)d_in[9];
    const float* g2  = (const float*)d_in[10];
    const float* bt2 = (const float*)d_in[11];
    const float* g3  = (const float*)d_in[12];
    const float* bt3 = (const float*)d_in[13];
    const float* Wc1 = (const float*)d_in[14];
    const float* bc1 = (const float*)d_in[15];
    const float* Wc2 = (const float*)d_in[16];
    const float* bc2 = (const float*)d_in[17];
    float* out = (float*)d_out;

    // ---- workspace carve-up ----
    const size_t SZH = (size_t)M * 128 * sizeof(u16);   // 25.6 MB
    char* ws = (char*)d_ws;
    u16* Y = (u16*)(ws);                     // GEMM output (bf16)
    u16* E = (u16*)(ws + SZH);               // edge features (bf16)
    u16* Z = (u16*)(ws + 2 * SZH);           // node agg, pre-BN (bf16)
    int* ib = (int*)(ws + 3 * SZH);
    int*   cb      = ib;                     // edge sizes / cursors [100000]
    int*   cd      = ib + 100000;            // node degrees / cursors
    int*   ovfCntB = ib + 200000;
    int*   ovfCntD = ib + 200001;
    int*   colB    = ib + 200016;            // 64-B aligned; [100000*16]
    int*   colD    = ib + 200016 + NE * CAP;
    uint2* ovfB    = (uint2*)(ib + 200016 + (NE + M) * CAP);
    uint2* ovfD    = ovfB + OVF_MAX;
    float* fb = (float*)(ovfD + OVF_MAX);
    float* gsum = fb;                        // [128]; gsq contiguous after
    u16* wbuf = (u16*)(fb + 256);
    u16* W1b = wbuf;                         // 2 chunks x 16384 (swizzled)
    u16* W2b = wbuf + 32768;                 // 1 chunk
    u16* W3b = wbuf + 49152;                 // 1 chunk

    const int ntiles = (M + 127) / 128;
    const float invM = 1.0f / (float)M;

    // ---- weight convert + counter zeroing (replaces the memset dispatch) ----
    convert_w<<<256, 256, 0, stream>>>(W1, W2, W3, W1b, W2b, W3b, cb);

    const float* gin[3]  = { g1, g2, g3 };
    const float* btin[3] = { bt1, bt2, bt3 };
    const u16*   Wbf[3]  = { W1b, W2b, W3b };

    for (int L = 0; L < 3; L++) {
        if (L == 0)
            // GEMM0 sharing its grid with FILLB dedicated fill blocks: the
            // scatter-atomic fill drains in separate waves, concurrent with
            // the MFMA/streaming work (dispatch ~= max, not sum).
            gemm_mfma<256, 1, 1><<<FILLB + ntiles, 256, 0, stream>>>(
                x, Wbf[0], Y, M, nullptr, nullptr, nullptr, nullptr, 0.0f,
                nidx, eidx, cb, cd, colB, colD, ovfB, ovfD, ovfCntB, ovfCntD, nnz);
        else
            gemm_mfma<128, 2, 0><<<ntiles, 256, 0, stream>>>(
                Z, Wbf[L], Y, M, gsum, gsum + 128, gin[L - 1], btin[L - 1], invM,
                nullptr, nullptr, nullptr, nullptr, nullptr, nullptr,
                nullptr, nullptr, nullptr, nullptr, 0);
        // edge aggregation; block 0 zeros gsum||gsq for the node pass
        gather_q<0><<<(NE + 15) / 16, 256, 0, stream>>>(
            Y, cb, colB, E, nullptr, gsum, ovfB, ovfCntB, NE);
        // node aggregation with fused raw-moment stats (2048 blocks = 8/CU)
        gather_q<1><<<2048, 256, 0, stream>>>(
            E, cd, colD, Z, gsum, nullptr, ovfD, ovfCntD, M);
    }

    classifier_mfma<<<ntiles, 256, 0, stream>>>(
        Z, Wc1, bc1, Wc2, bc2, out, M, gsum, gsum + 128, gin[2], btin[2], invM);
}

// Round 5
// 555.932 us; speedup vs baseline: 1.2245x; 1.0962x over previous
//
#include <hip/hip_runtime.h>

#define N_NODES 100000
#define N_EDGES 100000
#define NNZ_C   600000
#define CAP     16          // bucket = one 64-B line; overflow list handles tail
#define OVF_MAX 4096
#define NBIN    196         // bins of 512 ids: ceil(100000/512)
#define BINW    512
#define CAPB    4096        // staged items per bin (mean 3061, +18 sigma)
#define PA_ITEMS 4096       // pairs per pass-A block
#define PA_BLOCKS 147       // ceil(600000/4096)

typedef unsigned short u16;
typedef __attribute__((ext_vector_type(8))) short short8;
typedef __attribute__((ext_vector_type(4))) float float4v;

__device__ __forceinline__ void atomAddF(float* p, float v) {
    unsafeAtomicAdd(p, v);
}

__device__ __forceinline__ u16 f2bf(float f) {     // RNE fp32 -> bf16
    union { float f; unsigned int i; } x; x.f = f;
    unsigned int r = x.i + 0x7FFFu + ((x.i >> 16) & 1u);
    return (u16)(r >> 16);
}
__device__ __forceinline__ float bf2f(u16 u) {
    union { float f; unsigned int i; } x; x.i = ((unsigned int)u) << 16; return x.f;
}

__device__ __forceinline__ short8 cvt_frag(float4 a, float4 b) {
    union { short8 s; u16 u[8]; } o;
    o.u[0] = f2bf(a.x); o.u[1] = f2bf(a.y); o.u[2] = f2bf(a.z); o.u[3] = f2bf(a.w);
    o.u[4] = f2bf(b.x); o.u[5] = f2bf(b.y); o.u[6] = f2bf(b.z); o.u[7] = f2bf(b.w);
    return o.s;
}

// relu(z*A + C) per element; A/C indexed by the fragment's k offset
__device__ __forceinline__ short8 bn_frag(short8 raw, float4 A0, float4 A1,
                                          float4 C0, float4 C1) {
    union { short8 s; u16 u[8]; } in; in.s = raw;
    union { short8 s; u16 u[8]; } o;
    o.u[0] = f2bf(fmaxf(bf2f(in.u[0]) * A0.x + C0.x, 0.0f));
    o.u[1] = f2bf(fmaxf(bf2f(in.u[1]) * A0.y + C0.y, 0.0f));
    o.u[2] = f2bf(fmaxf(bf2f(in.u[2]) * A0.z + C0.z, 0.0f));
    o.u[3] = f2bf(fmaxf(bf2f(in.u[3]) * A0.w + C0.w, 0.0f));
    o.u[4] = f2bf(fmaxf(bf2f(in.u[4]) * A1.x + C1.x, 0.0f));
    o.u[5] = f2bf(fmaxf(bf2f(in.u[5]) * A1.y + C1.y, 0.0f));
    o.u[6] = f2bf(fmaxf(bf2f(in.u[6]) * A1.z + C1.z, 0.0f));
    o.u[7] = f2bf(fmaxf(bf2f(in.u[7]) * A1.w + C1.w, 0.0f));
    return o.s;
}

// ---------------- weights convert + fill pass A (LDS-binned scatter) --------
// Fill was 2.4M scattered atomic transactions (~95 us of fabric budget). New
// scheme: pass A bins the 600k (key,val) pairs into 196 bins of 512 ids via
// LDS histogram + scan + reorder, then writes bin-contiguous COALESCED
// segments to a staging area (~0.3M transactions). Pass B (in gemm0's grid)
// builds the buckets per-bin in LDS and streams them out coalesced.
// Staging lives in E (edge side) / Z (node side): both dead until after the
// gemm0 dispatch that contains pass B.
__global__ __launch_bounds__(256) void convert_binA(
    const float* __restrict__ W1, const float* __restrict__ W2,
    const float* __restrict__ W3, u16* __restrict__ W1b,
    u16* __restrict__ W2b, u16* __restrict__ W3b,
    const int* __restrict__ nidx, const int* __restrict__ eidx,
    uint2* __restrict__ stageB, uint2* __restrict__ stageD,
    int* __restrict__ gcur, int nnz)
{
    const int tid = threadIdx.x;
    if (blockIdx.x >= PA_BLOCKS) {
        // ---- weight-convert role: fp32 -> bf16, pre-swizzled LDS image
        // img[n*128 + rot(k,n)], rot = ((k/8 + n)&15)*8 + k%8, per 128-k chunk
        int i = (blockIdx.x - PA_BLOCKS) * 256 + tid;   // 65536 total
        const float* src; u16* dst; int idx;
        if      (i < 32768) { src = W1; dst = W1b; idx = i; }
        else if (i < 49152) { src = W2; dst = W2b; idx = i - 32768; }
        else                { src = W3; dst = W3b; idx = i - 49152; }
        int k = idx >> 7, n = idx & 127;
        int chunk = k >> 7, kl = k & 127;
        int kb = kl >> 3, kin = kl & 7;
        dst[chunk * 16384 + n * 128 + (((kb + n) & 15) << 3) + kin] = f2bf(src[idx]);
        return;
    }
    // ---- pass A role ----
    __shared__ uint2 its[PA_ITEMS];    // 32 KB
    __shared__ uint2 ord[PA_ITEMS];    // 32 KB
    __shared__ int hist[256], bscan[256], bfill[256], gbase[256];
    const int i0 = blockIdx.x * PA_ITEMS;
    int cnt = nnz - i0; if (cnt > PA_ITEMS) cnt = PA_ITEMS;

    for (int side = 0; side < 2; side++) {
        hist[tid] = 0;
        __syncthreads();
        for (int i = tid; i < cnt; i += 256) {
            int e = eidx[i0 + i], n = nidx[i0 + i];
            uint2 it = side ? make_uint2((unsigned)n, (unsigned)e)
                            : make_uint2((unsigned)e, (unsigned)n);
            its[i] = it;
            atomicAdd(&hist[it.x >> 9], 1);
        }
        __syncthreads();
        int v = hist[tid];
        // inclusive Hillis-Steele scan over 256 entries
        bscan[tid] = v;
        __syncthreads();
        for (int d = 1; d < 256; d <<= 1) {
            int t = (tid >= d) ? bscan[tid - d] : 0;
            __syncthreads();
            bscan[tid] += t;
            __syncthreads();
        }
        int myBase = bscan[tid] - v;   // exclusive
        if (tid < NBIN) gbase[tid] = atomicAdd(&gcur[side * NBIN + tid], v);
        __syncthreads();
        bscan[tid] = myBase;
        bfill[tid] = 0;
        __syncthreads();
        for (int i = tid; i < cnt; i += 256) {
            uint2 it = its[i];
            int b = it.x >> 9;
            int p = bscan[b] + atomicAdd(&bfill[b], 1);
            ord[p] = it;
        }
        __syncthreads();
        uint2* stg = side ? stageD : stageB;
        for (int i = tid; i < cnt; i += 256) {
            uint2 it = ord[i];
            int b = it.x >> 9;
            int pos = gbase[b] + (i - bscan[b]);   // within-bin position
            if (pos < CAPB) stg[b * CAPB + pos] = it;   // coalesced segments
        }
        __syncthreads();
    }
}

// ---------------- bf16 MFMA GEMM, optionally sharing its grid with fillB ----
// AMODE 1: A is fp32, convert in-register (GEMM0).
// AMODE 2: A is bf16 pre-BN z; apply relu(z*As+Cs), As/Cs from raw moments.
// DOFILL : blocks [0, 2*NBIN) are fill pass-B blocks, one per (side,bin):
//          read ~3k staged items coalesced, build the bin's 512 buckets in
//          LDS (LDS atomics), stream colB/colD + counts out coalesced.
//          ~0.2M fabric transactions total vs 2.4M for the old per-pair
//          atomic scatter. Role split by blockIdx keeps the gemm waves'
//          vmcnt independent of the fill traffic.
template<int KDIM, int AMODE, int DOFILL>
__global__ __launch_bounds__(256) void gemm_mfma(
    const void* __restrict__ Aptr, const u16* __restrict__ Wb,
    u16* __restrict__ C, int M,
    const float* __restrict__ gsum, const float* __restrict__ gsq,
    const float* __restrict__ gam, const float* __restrict__ bet, float invM,
    const uint2* __restrict__ stageB, const uint2* __restrict__ stageD,
    const int* __restrict__ gcur,
    int* __restrict__ cbp, int* __restrict__ cdp,
    int* __restrict__ colBp, int* __restrict__ colDp,
    uint2* __restrict__ ovfBp, uint2* __restrict__ ovfDp,
    int* __restrict__ ovfCBp, int* __restrict__ ovfCDp)
{
    __shared__ __attribute__((aligned(16))) char smem[51200];
    const int tid = threadIdx.x;

    if (DOFILL && blockIdx.x < 2 * NBIN) {
        // ---- fill pass B role ----
        const int side = (blockIdx.x >= NBIN) ? 1 : 0;
        const int bin  = (int)blockIdx.x - side * NBIN;
        const uint2* stg = side ? stageD : stageB;
        int nIt = gcur[side * NBIN + bin]; if (nIt > CAPB) nIt = CAPB;
        const int base = bin << 9;
        int nk = N_NODES - base; if (nk > BINW) nk = BINW;
        int*   lcnt  = (int*)smem;              // 512 * 4 = 2 KB
        int*   lbuck = (int*)(smem + 2048);     // 512 * 16 * 4 = 32 KB
        for (int j = tid; j < BINW; j += 256) lcnt[j] = 0;
        __syncthreads();
        int*   ovfC = side ? ovfCDp : ovfCBp;
        uint2* ovfA = side ? ovfDp : ovfBp;
        for (int i = tid; i < nIt; i += 256) {
            uint2 it = stg[bin * CAPB + i];
            int kl = (int)it.x - base;
            int s = atomicAdd(&lcnt[kl], 1);
            if (s < CAP) lbuck[(kl << 4) + s] = (int)it.y;
            else { int o = atomicAdd(ovfC, 1); if (o < OVF_MAX) ovfA[o] = it; }
        }
        __syncthreads();
        int* cp   = side ? cdp : cbp;
        int* colp = side ? colDp : colBp;
        for (int j = tid; j < nk; j += 256) cp[base + j] = lcnt[j];
        for (int j = tid; j < (nk << 4); j += 256) colp[(base << 4) + j] = lbuck[j];
        return;
    }
    const int bx = DOFILL ? ((int)blockIdx.x - 2 * NBIN) : (int)blockIdx.x;

    u16* Wt = (u16*)smem;                               // 32 KB
    u16 (*tb)[16][136] = (u16(*)[16][136])(smem + 32768); // 17 KB
    float* As = (float*)(smem + 32768 + 17408);
    float* Cs = As + 128;

    if (AMODE == 2 && tid < 128) {
        float s1 = gsum[tid] * invM;
        float var = gsq[tid] * invM - s1 * s1;
        if (var < 0.0f) var = 0.0f;
        float sc = gam[tid] * rsqrtf(var + 1e-5f);
        As[tid] = sc;
        Cs[tid] = bet[tid] - s1 * sc;   // conv bias cancels under BN
    }
    const int wave = tid >> 6, lane = tid & 63;
    const int l16 = lane & 15, quad = lane >> 4;
    const int rowt = bx * 128 + wave * 32;
    const int r0 = rowt + l16, r1 = rowt + 16 + l16;
    const bool v0 = r0 < M, v1 = r1 < M;
    const u16*   Ab = (const u16*)Aptr;
    const float* Af = (const float*)Aptr;
    const size_t rb0 = (size_t)(v0 ? r0 : 0) * KDIM + quad * 8;
    const size_t rb1 = (size_t)(v1 ? r1 : 0) * KDIM + quad * 8;

    float4v acc[2][8];
#pragma unroll
    for (int g = 0; g < 2; g++)
#pragma unroll
        for (int c = 0; c < 8; c++) acc[g][c] = (float4v)0.0f;

    for (int kc = 0; kc < KDIM; kc += 128) {
        if (kc) __syncthreads();
        {
            const uint4* Wsrc = (const uint4*)Wb + (kc >> 7) * 2048;
            uint4* Wdst = (uint4*)Wt;
            for (int i = tid; i < 2048; i += 256) Wdst[i] = Wsrc[i];
        }
        __syncthreads();
        for (int k0 = 0; k0 < 128; k0 += 32) {
            short8 af0, af1;
            if (AMODE == 1) {
                af0 = cvt_frag(*(const float4*)(Af + rb0 + kc + k0),
                               *(const float4*)(Af + rb0 + kc + k0 + 4));
                af1 = cvt_frag(*(const float4*)(Af + rb1 + kc + k0),
                               *(const float4*)(Af + rb1 + kc + k0 + 4));
            } else {
                int kb4 = k0 + quad * 8;
                float4 A0 = *(const float4*)&As[kb4], A1 = *(const float4*)&As[kb4 + 4];
                float4 C0 = *(const float4*)&Cs[kb4], C1 = *(const float4*)&Cs[kb4 + 4];
                af0 = bn_frag(*(const short8*)(Ab + rb0 + k0), A0, A1, C0, C1);
                af1 = bn_frag(*(const short8*)(Ab + rb1 + k0), A0, A1, C0, C1);
            }
            if (!v0) af0 = (short8)(short)0;
            if (!v1) af1 = (short8)(short)0;
            const int kb = (k0 >> 3) + quad;
#pragma unroll
            for (int c = 0; c < 8; c++) {
                const int n = c * 16 + l16;
                short8 bf = *(const short8*)&Wt[n * 128 + (((kb + n) & 15) << 3)];
                acc[0][c] = __builtin_amdgcn_mfma_f32_16x16x32_bf16(af0, bf, acc[0][c], 0, 0, 0);
                acc[1][c] = __builtin_amdgcn_mfma_f32_16x16x32_bf16(af1, bf, acc[1][c], 0, 0, 0);
            }
        }
    }
#pragma unroll
    for (int g = 0; g < 2; g++) {
#pragma unroll
        for (int c = 0; c < 8; c++)
#pragma unroll
            for (int r = 0; r < 4; r++)
                tb[wave][quad * 4 + r][c * 16 + l16] = f2bf(acc[g][c][r]);
        asm volatile("s_waitcnt lgkmcnt(0)" ::: "memory");
#pragma unroll
        for (int j = 0; j < 4; j++) {
            int row_l = j * 4 + (lane >> 4);
            int row = rowt + g * 16 + row_l;
            if (row < M) {
                short8 vv = *(const short8*)&tb[wave][row_l][(lane & 15) * 8];
                *(short8*)(C + (size_t)row * 128 + (lane & 15) * 8) = vv;
            }
        }
        if (g == 0) asm volatile("s_waitcnt lgkmcnt(0)" ::: "memory");
    }
}

// ---------------- quarter-wave gather: 16 lanes/row, uint4 (8 bf16)/lane ----
// dst[r] = (1/cnt[r]) * sum src[members]; 4 rows per wave, 16 B/lane loads.
// cnt and col load concurrently (col read unconditionally; garbage lanes are
// never shfl-selected); the member loop always issues a full clamp-and-mask
// group of 4 (clamped lanes re-read the last member's line — TA dedups
// same-line lanes — and are masked to 0 before accumulation).
// STATS: per-lane 8-column raw moments -> LDS -> one 256-atomic flush/block.
template<int STATS>
__global__ __launch_bounds__(256) void gather_q(
    const u16* __restrict__ src, const int* __restrict__ cnt,
    const int* __restrict__ col, u16* __restrict__ dst,
    float* __restrict__ stat, float* __restrict__ zp,
    const uint2* __restrict__ ovf, const int* __restrict__ ovfCnt, int nrows)
{
    if (zp && blockIdx.x == 0) zp[threadIdx.x] = 0.0f;
    const int tid  = threadIdx.x;
    const int lane = tid & 63;
    const int ql   = lane & 15;       // lane within quarter
    const int qid  = tid >> 4;        // quarter id within block, 0..15
    const int bsel = lane & 48;       // shfl base for this quarter
    const u16* srcq = src + ql * 8;   // this lane's 8 columns
    float s1[8] = {0,0,0,0,0,0,0,0};
    float s2[8] = {0,0,0,0,0,0,0,0};

    for (int rr = blockIdx.x * 16; rr < nrows; rr += gridDim.x * 16) {
        int r = rr + qid;
        if (r < nrows) {
            int c = cnt[r];
            int m = col[(r << 4) + ql];      // issues concurrently with cnt
            int cc = (c > CAP) ? CAP : c;
            float a[8] = {0,0,0,0,0,0,0,0};
            int cl = cc - 1;
            for (int j = 0; j < cc; j += 4) {
                int i1 = (j + 1 > cl) ? cl : j + 1;
                int i2 = (j + 2 > cl) ? cl : j + 2;
                int i3 = (j + 3 > cl) ? cl : j + 3;
                int t0 = __shfl(m, bsel | j);
                int t1 = __shfl(m, bsel | i1);
                int t2 = __shfl(m, bsel | i2);
                int t3 = __shfl(m, bsel | i3);
                uint4 va = *(const uint4*)(srcq + (size_t)t0 * 128);
                uint4 vb = *(const uint4*)(srcq + (size_t)t1 * 128);
                uint4 vc = *(const uint4*)(srcq + (size_t)t2 * 128);
                uint4 vd = *(const uint4*)(srcq + (size_t)t3 * 128);
                if (j + 1 > cl) vb = make_uint4(0, 0, 0, 0);
                if (j + 2 > cl) vc = make_uint4(0, 0, 0, 0);
                if (j + 3 > cl) vd = make_uint4(0, 0, 0, 0);
                a[0] += bf2f((u16)(va.x & 0xFFFF)) + bf2f((u16)(vb.x & 0xFFFF))
                      + bf2f((u16)(vc.x & 0xFFFF)) + bf2f((u16)(vd.x & 0xFFFF));
                a[1] += bf2f((u16)(va.x >> 16)) + bf2f((u16)(vb.x >> 16))
                      + bf2f((u16)(vc.x >> 16)) + bf2f((u16)(vd.x >> 16));
                a[2] += bf2f((u16)(va.y & 0xFFFF)) + bf2f((u16)(vb.y & 0xFFFF))
                      + bf2f((u16)(vc.y & 0xFFFF)) + bf2f((u16)(vd.y & 0xFFFF));
                a[3] += bf2f((u16)(va.y >> 16)) + bf2f((u16)(vb.y >> 16))
                      + bf2f((u16)(vc.y >> 16)) + bf2f((u16)(vd.y >> 16));
                a[4] += bf2f((u16)(va.z & 0xFFFF)) + bf2f((u16)(vb.z & 0xFFFF))
                      + bf2f((u16)(vc.z & 0xFFFF)) + bf2f((u16)(vd.z & 0xFFFF));
                a[5] += bf2f((u16)(va.z >> 16)) + bf2f((u16)(vb.z >> 16))
                      + bf2f((u16)(vc.z >> 16)) + bf2f((u16)(vd.z >> 16));
                a[6] += bf2f((u16)(va.w & 0xFFFF)) + bf2f((u16)(vb.w & 0xFFFF))
                      + bf2f((u16)(vc.w & 0xFFFF)) + bf2f((u16)(vd.w & 0xFFFF));
                a[7] += bf2f((u16)(va.w >> 16)) + bf2f((u16)(vb.w >> 16))
                      + bf2f((u16)(vc.w >> 16)) + bf2f((u16)(vd.w >> 16));
            }
            if (c > CAP) {                 // rare: scan overflow list
                int nov = *ovfCnt; if (nov > OVF_MAX) nov = OVF_MAX;
                for (int i2 = 0; i2 < nov; i2++) {
                    uint2 p = ovf[i2];
                    if ((int)p.x == r) {
                        uint4 va = *(const uint4*)(srcq + (size_t)p.y * 128);
                        a[0] += bf2f((u16)(va.x & 0xFFFF)); a[1] += bf2f((u16)(va.x >> 16));
                        a[2] += bf2f((u16)(va.y & 0xFFFF)); a[3] += bf2f((u16)(va.y >> 16));
                        a[4] += bf2f((u16)(va.z & 0xFFFF)); a[5] += bf2f((u16)(va.z >> 16));
                        a[6] += bf2f((u16)(va.w & 0xFFFF)); a[7] += bf2f((u16)(va.w >> 16));
                    }
                }
            }
            float w = (c > 0) ? 1.0f / (float)c : 0.0f;
#pragma unroll
            for (int k = 0; k < 8; k++) a[k] *= w;
            uint4 o;
            o.x = (unsigned)f2bf(a[0]) | ((unsigned)f2bf(a[1]) << 16);
            o.y = (unsigned)f2bf(a[2]) | ((unsigned)f2bf(a[3]) << 16);
            o.z = (unsigned)f2bf(a[4]) | ((unsigned)f2bf(a[5]) << 16);
            o.w = (unsigned)f2bf(a[6]) | ((unsigned)f2bf(a[7]) << 16);
            *(uint4*)(dst + (size_t)r * 128 + ql * 8) = o;
            if (STATS) {
#pragma unroll
                for (int k = 0; k < 8; k++) { s1[k] += a[k]; s2[k] += a[k] * a[k]; }
            }
        }
    }
    if (STATS) {
        __shared__ float redS[16][128];
        __shared__ float redQ[16][128];
#pragma unroll
        for (int k = 0; k < 8; k++) {
            redS[qid][ql * 8 + k] = s1[k];
            redQ[qid][ql * 8 + k] = s2[k];
        }
        __syncthreads();
        int t = tid & 127;
        float accv = 0.0f;
        if (tid < 128) {
#pragma unroll
            for (int q = 0; q < 16; q++) accv += redS[q][t];
            atomAddF(&stat[t], accv);
        } else {
#pragma unroll
            for (int q = 0; q < 16; q++) accv += redQ[q][t];
            atomAddF(&stat[128 + t], accv);
        }
    }
}

// ---------------- MFMA classifier with fused BN on the A-path ---------------
__global__ __launch_bounds__(256) void classifier_mfma(
    const u16* __restrict__ Z, const float* __restrict__ Wc1,
    const float* __restrict__ bc1, const float* __restrict__ Wc2,
    const float* __restrict__ bc2, float* __restrict__ out, int M,
    const float* __restrict__ gsum, const float* __restrict__ gsq,
    const float* __restrict__ gam, const float* __restrict__ bet, float invM)
{
    __shared__ __attribute__((aligned(16))) u16 W1t[64 * 128];   // 16 KB
    __shared__ __attribute__((aligned(16))) u16 W2t[16 * 64];    // 2 KB
    __shared__ __attribute__((aligned(16))) u16 hs[128][72];     // 18.4 KB
    __shared__ __attribute__((aligned(16))) float As[128];
    __shared__ __attribute__((aligned(16))) float Cs[128];
    const int tid = threadIdx.x;
    if (tid < 128) {
        float s1 = gsum[tid] * invM;
        float var = gsq[tid] * invM - s1 * s1;
        if (var < 0.0f) var = 0.0f;
        float sc = gam[tid] * rsqrtf(var + 1e-5f);
        As[tid] = sc;
        Cs[tid] = bet[tid] - s1 * sc;
    }
    for (int i = tid; i < 64 * 128; i += 256) {   // i = k*64 + n
        int k = i >> 6, n = i & 63;
        int kb = k >> 3, kin = k & 7;
        W1t[n * 128 + (((kb + n) & 15) << 3) + kin] = f2bf(Wc1[i]);
    }
    for (int i = tid; i < 16 * 64; i += 256) {    // i = k*16 + n
        int k = i >> 4, n = i & 15;
        W2t[n * 64 + k] = (n < 10) ? f2bf(Wc2[k * 10 + n]) : (u16)0;
    }
    __syncthreads();

    const int wave = tid >> 6, lane = tid & 63;
    const int l16 = lane & 15, quad = lane >> 4;
    const int rowt = blockIdx.x * 128 + wave * 32;
    const int r0 = rowt + l16, r1 = rowt + 16 + l16;
    const bool v0 = r0 < M, v1 = r1 < M;
    const u16* a0p = Z + (size_t)(v0 ? r0 : 0) * 128 + quad * 8;
    const u16* a1p = Z + (size_t)(v1 ? r1 : 0) * 128 + quad * 8;

    float4v acc[2][4];
#pragma unroll
    for (int g = 0; g < 2; g++)
#pragma unroll
        for (int c = 0; c < 4; c++) acc[g][c] = (float4v)0.0f;

#pragma unroll
    for (int k0 = 0; k0 < 128; k0 += 32) {
        int kb4 = k0 + quad * 8;
        float4 A0 = *(const float4*)&As[kb4], A1 = *(const float4*)&As[kb4 + 4];
        float4 C0 = *(const float4*)&Cs[kb4], C1 = *(const float4*)&Cs[kb4 + 4];
        short8 af0 = bn_frag(*(const short8*)(a0p + k0), A0, A1, C0, C1);
        short8 af1 = bn_frag(*(const short8*)(a1p + k0), A0, A1, C0, C1);
        if (!v0) af0 = (short8)(short)0;
        if (!v1) af1 = (short8)(short)0;
        const int kb = (k0 >> 3) + quad;
#pragma unroll
        for (int c = 0; c < 4; c++) {
            const int n = c * 16 + l16;
            short8 bf = *(const short8*)&W1t[n * 128 + (((kb + n) & 15) << 3)];
            acc[0][c] = __builtin_amdgcn_mfma_f32_16x16x32_bf16(af0, bf, acc[0][c], 0, 0, 0);
            acc[1][c] = __builtin_amdgcn_mfma_f32_16x16x32_bf16(af1, bf, acc[1][c], 0, 0, 0);
        }
    }
#pragma unroll
    for (int g = 0; g < 2; g++)
#pragma unroll
        for (int c = 0; c < 4; c++) {
            float b = bc1[c * 16 + l16];
#pragma unroll
            for (int r = 0; r < 4; r++)
                hs[wave * 32 + g * 16 + quad * 4 + r][c * 16 + l16] =
                    f2bf(fmaxf(acc[g][c][r] + b, 0.0f));
        }
    asm volatile("s_waitcnt lgkmcnt(0)" ::: "memory");

    float4v a2[2];
    a2[0] = (float4v)0.0f; a2[1] = (float4v)0.0f;
#pragma unroll
    for (int k0 = 0; k0 < 64; k0 += 32) {
        short8 bf = *(const short8*)&W2t[l16 * 64 + k0 + quad * 8];
#pragma unroll
        for (int g = 0; g < 2; g++) {
            short8 af = *(const short8*)&hs[wave * 32 + g * 16 + l16][k0 + quad * 8];
            a2[g] = __builtin_amdgcn_mfma_f32_16x16x32_bf16(af, bf, a2[g], 0, 0, 0);
        }
    }
    if (l16 < 10) {
        float b2 = bc2[l16];
#pragma unroll
        for (int g = 0; g < 2; g++)
#pragma unroll
            for (int r = 0; r < 4; r++) {
                int row = rowt + g * 16 + quad * 4 + r;
                if (row < M) out[(size_t)row * 10 + l16] = a2[g][r] + b2;
            }
    }
}

// ---------------- launch ----------------------------------------------------
extern "C" void kernel_launch(void* const* d_in, const int* in_sizes, int n_in,
                              void* d_out, int out_size, void* d_ws, size_t ws_size,
                              hipStream_t stream)
{
    const int M   = N_NODES;
    const int NE  = N_EDGES;
    const int nnz = NNZ_C;

    const float* x   = (const float*)d_in[0];
    const int*  nidx = (const int*)d_in[1];
    const int*  eidx = nidx + nnz;
    const float* W1  = (const float*)d_in[2];
    const float* W2  = (const float*)d_in[4];
    const float* W3  = (const float*)d_in[6];
    const float* g1  = (const float*)d_in[8];
    const float* bt1 = (const float*)d_in[9];
    const float* g2  = (const float*)d_in[10];
    const float* bt2 = (const float*)d_in[11];
    const float* g3  = (const float*)d_in[12];
    const float* bt3 = (const float*)d_in[13];
    const float* Wc1 = (const float*)d_in[14];
    const float* bc1 = (const float*)d_in[15];
    const float* Wc2 = (const float*)d_in[16];
    const float* bc2 = (const float*)d_in[17];
    float* out = (float*)d_out;

    // ---- workspace carve-up ----
    const size_t SZH = (size_t)M * 128 * sizeof(u16);   // 25.6 MB
    char* ws = (char*)d_ws;
    u16* Y = (u16*)(ws);                     // GEMM output (bf16)
    u16* E = (u16*)(ws + SZH);               // edge features (bf16)
    u16* Z = (u16*)(ws + 2 * SZH);           // node agg, pre-BN (bf16)
    int* ib = (int*)(ws + 3 * SZH);
    int*   cb      = ib;                     // edge sizes [100000]
    int*   cd      = ib + 100000;            // node degrees
    int*   colB    = ib + 200016;            // 64-B aligned; [100000*16]
    int*   colD    = ib + 200016 + NE * CAP;
    uint2* ovfB    = (uint2*)(ib + 200016 + (NE + M) * CAP);
    uint2* ovfD    = ovfB + OVF_MAX;
    float* fb = (float*)(ovfD + OVF_MAX);
    float* gsum = fb;                        // [128]; gsq contiguous after
    u16* wbuf = (u16*)(fb + 256);
    u16* W1b = wbuf;                         // 2 chunks x 16384 (swizzled)
    u16* W2b = wbuf + 32768;                 // 1 chunk
    u16* W3b = wbuf + 49152;                 // 1 chunk
    int* gq  = (int*)(wbuf + 65536);         // [2*NBIN cursors][2 ovf counters]
    int* ovfCntB = gq + 2 * NBIN;
    int* ovfCntD = gq + 2 * NBIN + 1;
    // staging lives in E/Z (dead until after the gemm0 dispatch runs pass B)
    uint2* stageB = (uint2*)E;               // 196*4096*8 = 6.42 MB
    uint2* stageD = (uint2*)Z;

    const int ntiles = (M + 127) / 128;
    const float invM = 1.0f / (float)M;

    // zero bin cursors + overflow counters (tiny)
    hipMemsetAsync(gq, 0, (2 * NBIN + 2) * sizeof(int), stream);

    // ---- weight convert + fill pass A (role-split grid) ----
    convert_binA<<<PA_BLOCKS + 256, 256, 0, stream>>>(
        W1, W2, W3, W1b, W2b, W3b, nidx, eidx, stageB, stageD, gq, nnz);

    const float* gin[3]  = { g1, g2, g3 };
    const float* btin[3] = { bt1, bt2, bt3 };
    const u16*   Wbf[3]  = { W1b, W2b, W3b };

    for (int L = 0; L < 3; L++) {
        if (L == 0)
            // GEMM0 sharing its grid with 2*NBIN fill pass-B blocks
            gemm_mfma<256, 1, 1><<<2 * NBIN + ntiles, 256, 0, stream>>>(
                x, Wbf[0], Y, M, nullptr, nullptr, nullptr, nullptr, 0.0f,
                stageB, stageD, gq, cb, cd, colB, colD, ovfB, ovfD,
                ovfCntB, ovfCntD);
        else
            gemm_mfma<128, 2, 0><<<ntiles, 256, 0, stream>>>(
                Z, Wbf[L], Y, M, gsum, gsum + 128, gin[L - 1], btin[L - 1], invM,
                nullptr, nullptr, nullptr, nullptr, nullptr, nullptr, nullptr,
                nullptr, nullptr, nullptr, nullptr);
        // edge aggregation; block 0 zeros gsum||gsq for the node pass
        gather_q<0><<<(NE + 15) / 16, 256, 0, stream>>>(
            Y, cb, colB, E, nullptr, gsum, ovfB, ovfCntB, NE);
        // node aggregation with fused raw-moment stats (2048 blocks = 8/CU)
        gather_q<1><<<2048, 256, 0, stream>>>(
            E, cd, colD, Z, gsum, nullptr, ovfD, ovfCntD, M);
    }

    classifier_mfma<<<ntiles, 256, 0, stream>>>(
        Z, Wc1, bc1, Wc2, bc2, out, M, gsum, gsum + 128, gin[2], btin[2], invM);
}

// Round 7
// 553.035 us; speedup vs baseline: 1.2310x; 1.0052x over previous
//
#include <hip/hip_runtime.h>

#define N_NODES 100000
#define N_EDGES 100000
#define NNZ_C   600000
#define CAP     16          // bucket = one 64-B line; overflow list handles tail
#define OVF_MAX 4096
#define NBIN    196         // bins of 512 ids: ceil(100000/512)
#define BINW    512
#define CAPB    4096        // staged items per bin (mean 3061, +18 sigma)
#define PA_ITEMS 4096       // pairs per pass-A block
#define PA_BLOCKS 147       // ceil(600000/4096)

typedef unsigned short u16;
typedef __attribute__((ext_vector_type(8))) short short8;
typedef __attribute__((ext_vector_type(4))) float float4v;

__device__ __forceinline__ void atomAddF(float* p, float v) {
    unsafeAtomicAdd(p, v);
}

__device__ __forceinline__ u16 f2bf(float f) {     // RNE fp32 -> bf16
    union { float f; unsigned int i; } x; x.f = f;
    unsigned int r = x.i + 0x7FFFu + ((x.i >> 16) & 1u);
    return (u16)(r >> 16);
}
__device__ __forceinline__ float bf2f(u16 u) {
    union { float f; unsigned int i; } x; x.i = ((unsigned int)u) << 16; return x.f;
}

__device__ __forceinline__ short8 cvt_frag(float4 a, float4 b) {
    union { short8 s; u16 u[8]; } o;
    o.u[0] = f2bf(a.x); o.u[1] = f2bf(a.y); o.u[2] = f2bf(a.z); o.u[3] = f2bf(a.w);
    o.u[4] = f2bf(b.x); o.u[5] = f2bf(b.y); o.u[6] = f2bf(b.z); o.u[7] = f2bf(b.w);
    return o.s;
}

// relu(z*A + C) per element; A/C indexed by the fragment's k offset
__device__ __forceinline__ short8 bn_frag(short8 raw, float4 A0, float4 A1,
                                          float4 C0, float4 C1) {
    union { short8 s; u16 u[8]; } in; in.s = raw;
    union { short8 s; u16 u[8]; } o;
    o.u[0] = f2bf(fmaxf(bf2f(in.u[0]) * A0.x + C0.x, 0.0f));
    o.u[1] = f2bf(fmaxf(bf2f(in.u[1]) * A0.y + C0.y, 0.0f));
    o.u[2] = f2bf(fmaxf(bf2f(in.u[2]) * A0.z + C0.z, 0.0f));
    o.u[3] = f2bf(fmaxf(bf2f(in.u[3]) * A0.w + C0.w, 0.0f));
    o.u[4] = f2bf(fmaxf(bf2f(in.u[4]) * A1.x + C1.x, 0.0f));
    o.u[5] = f2bf(fmaxf(bf2f(in.u[5]) * A1.y + C1.y, 0.0f));
    o.u[6] = f2bf(fmaxf(bf2f(in.u[6]) * A1.z + C1.z, 0.0f));
    o.u[7] = f2bf(fmaxf(bf2f(in.u[7]) * A1.w + C1.w, 0.0f));
    return o.s;
}

__device__ __forceinline__ void acc8_bf(float* a, uint4 v) {
    a[0] += bf2f((u16)(v.x & 0xFFFF)); a[1] += bf2f((u16)(v.x >> 16));
    a[2] += bf2f((u16)(v.y & 0xFFFF)); a[3] += bf2f((u16)(v.y >> 16));
    a[4] += bf2f((u16)(v.z & 0xFFFF)); a[5] += bf2f((u16)(v.z >> 16));
    a[6] += bf2f((u16)(v.w & 0xFFFF)); a[7] += bf2f((u16)(v.w >> 16));
}

// ---------------- weights convert + fill pass A (LDS-binned scatter) --------
// Pass A bins the 600k (key,val) pairs into 196 bins of 512 ids via LDS
// histogram + scan + reorder, then writes bin-contiguous COALESCED segments.
// Each block handles ONE side (edge/node) of ONE chunk (sides parallel).
__global__ __launch_bounds__(256) void convert_binA(
    const float* __restrict__ W1, const float* __restrict__ W2,
    const float* __restrict__ W3, u16* __restrict__ W1b,
    u16* __restrict__ W2b, u16* __restrict__ W3b,
    const int* __restrict__ nidx, const int* __restrict__ eidx,
    uint2* __restrict__ stageB, uint2* __restrict__ stageD,
    int* __restrict__ gcur, int nnz)
{
    const int tid = threadIdx.x;
    if (blockIdx.x >= 2 * PA_BLOCKS) {
        // ---- weight-convert role: fp32 -> bf16, pre-swizzled LDS image
        int i = (blockIdx.x - 2 * PA_BLOCKS) * 256 + tid;   // 65536 total
        const float* src; u16* dst; int idx;
        if      (i < 32768) { src = W1; dst = W1b; idx = i; }
        else if (i < 49152) { src = W2; dst = W2b; idx = i - 32768; }
        else                { src = W3; dst = W3b; idx = i - 49152; }
        int k = idx >> 7, n = idx & 127;
        int chunk = k >> 7, kl = k & 127;
        int kb = kl >> 3, kin = kl & 7;
        dst[chunk * 16384 + n * 128 + (((kb + n) & 15) << 3) + kin] = f2bf(src[idx]);
        return;
    }
    // ---- pass A role: one (side, chunk) per block ----
    const int side  = (blockIdx.x >= PA_BLOCKS) ? 1 : 0;
    const int chunk = (int)blockIdx.x - side * PA_BLOCKS;
    __shared__ uint2 its[PA_ITEMS];    // 32 KB
    __shared__ uint2 ord[PA_ITEMS];    // 32 KB
    __shared__ int hist[256], bscan[256], bfill[256], gbase[256];
    const int i0 = chunk * PA_ITEMS;
    int cnt = nnz - i0; if (cnt > PA_ITEMS) cnt = PA_ITEMS;

    hist[tid] = 0;
    __syncthreads();
    for (int i = tid; i < cnt; i += 256) {
        int e = eidx[i0 + i], n = nidx[i0 + i];
        uint2 it = side ? make_uint2((unsigned)n, (unsigned)e)
                        : make_uint2((unsigned)e, (unsigned)n);
        its[i] = it;
        atomicAdd(&hist[it.x >> 9], 1);
    }
    __syncthreads();
    int v = hist[tid];
    bscan[tid] = v;                    // inclusive Hillis-Steele scan
    __syncthreads();
    for (int d = 1; d < 256; d <<= 1) {
        int t = (tid >= d) ? bscan[tid - d] : 0;
        __syncthreads();
        bscan[tid] += t;
        __syncthreads();
    }
    int myBase = bscan[tid] - v;       // exclusive
    if (tid < NBIN) gbase[tid] = atomicAdd(&gcur[side * NBIN + tid], v);
    __syncthreads();
    bscan[tid] = myBase;
    bfill[tid] = 0;
    __syncthreads();
    for (int i = tid; i < cnt; i += 256) {
        uint2 it = its[i];
        int b = it.x >> 9;
        int p = bscan[b] + atomicAdd(&bfill[b], 1);
        ord[p] = it;
    }
    __syncthreads();
    uint2* stg = side ? stageD : stageB;
    for (int i = tid; i < cnt; i += 256) {
        uint2 it = ord[i];
        int b = it.x >> 9;
        int pos = gbase[b] + (i - bscan[b]);   // within-bin position
        if (pos < CAPB) stg[b * CAPB + pos] = it;   // coalesced segments
    }
}

// ---------------- bf16 MFMA GEMM, optionally sharing its grid with fillB ----
// AMODE 1: A is fp32, convert in-register (GEMM0).
// AMODE 2: A is bf16 pre-BN z; apply relu(z*As+Cs), As/Cs from raw moments.
// DOFILL : blocks [0, 2*NBIN) are fill pass-B blocks, one per (side,bin):
//          read ~3k staged items coalesced, build the bin's 512 buckets in
//          LDS (LDS atomics), stream colB/colD + counts out coalesced.
template<int KDIM, int AMODE, int DOFILL>
__global__ __launch_bounds__(256) void gemm_mfma(
    const void* __restrict__ Aptr, const u16* __restrict__ Wb,
    u16* __restrict__ C, int M,
    const float* __restrict__ gsum, const float* __restrict__ gsq,
    const float* __restrict__ gam, const float* __restrict__ bet, float invM,
    const uint2* __restrict__ stageB, const uint2* __restrict__ stageD,
    const int* __restrict__ gcur,
    int* __restrict__ cbp, int* __restrict__ cdp,
    int* __restrict__ colBp, int* __restrict__ colDp,
    uint2* __restrict__ ovfBp, uint2* __restrict__ ovfDp,
    int* __restrict__ ovfCBp, int* __restrict__ ovfCDp)
{
    __shared__ __attribute__((aligned(16))) char smem[51200];
    const int tid = threadIdx.x;

    if (DOFILL && blockIdx.x < 2 * NBIN) {
        // ---- fill pass B role ----
        const int side = (blockIdx.x >= NBIN) ? 1 : 0;
        const int bin  = (int)blockIdx.x - side * NBIN;
        const uint2* stg = side ? stageD : stageB;
        int nIt = gcur[side * NBIN + bin]; if (nIt > CAPB) nIt = CAPB;
        const int base = bin << 9;
        int nk = N_NODES - base; if (nk > BINW) nk = BINW;
        int*   lcnt  = (int*)smem;              // 512 * 4 = 2 KB
        int*   lbuck = (int*)(smem + 2048);     // 512 * 16 * 4 = 32 KB
        for (int j = tid; j < BINW; j += 256) lcnt[j] = 0;
        __syncthreads();
        int*   ovfC = side ? ovfCDp : ovfCBp;
        uint2* ovfA = side ? ovfDp : ovfBp;
        for (int i = tid; i < nIt; i += 256) {
            uint2 it = stg[bin * CAPB + i];
            int kl = (int)it.x - base;
            int s = atomicAdd(&lcnt[kl], 1);
            if (s < CAP) lbuck[(kl << 4) + s] = (int)it.y;
            else { int o = atomicAdd(ovfC, 1); if (o < OVF_MAX) ovfA[o] = it; }
        }
        __syncthreads();
        int* cp   = side ? cdp : cbp;
        int* colp = side ? colDp : colBp;
        for (int j = tid; j < nk; j += 256) cp[base + j] = lcnt[j];
        for (int j = tid; j < (nk << 4); j += 256) colp[(base << 4) + j] = lbuck[j];
        return;
    }
    const int bx = DOFILL ? ((int)blockIdx.x - 2 * NBIN) : (int)blockIdx.x;

    u16* Wt = (u16*)smem;                               // 32 KB
    u16 (*tb)[16][136] = (u16(*)[16][136])(smem + 32768); // 17 KB
    float* As = (float*)(smem + 32768 + 17408);
    float* Cs = As + 128;

    if (AMODE == 2 && tid < 128) {
        float s1 = gsum[tid] * invM;
        float var = gsq[tid] * invM - s1 * s1;
        if (var < 0.0f) var = 0.0f;
        float sc = gam[tid] * rsqrtf(var + 1e-5f);
        As[tid] = sc;
        Cs[tid] = bet[tid] - s1 * sc;   // conv bias cancels under BN
    }
    const int wave = tid >> 6, lane = tid & 63;
    const int l16 = lane & 15, quad = lane >> 4;
    const int rowt = bx * 128 + wave * 32;
    const int r0 = rowt + l16, r1 = rowt + 16 + l16;
    const bool v0 = r0 < M, v1 = r1 < M;
    const u16*   Ab = (const u16*)Aptr;
    const float* Af = (const float*)Aptr;
    const size_t rb0 = (size_t)(v0 ? r0 : 0) * KDIM + quad * 8;
    const size_t rb1 = (size_t)(v1 ? r1 : 0) * KDIM + quad * 8;

    float4v acc[2][8];
#pragma unroll
    for (int g = 0; g < 2; g++)
#pragma unroll
        for (int c = 0; c < 8; c++) acc[g][c] = (float4v)0.0f;

    for (int kc = 0; kc < KDIM; kc += 128) {
        if (kc) __syncthreads();
        {
            const uint4* Wsrc = (const uint4*)Wb + (kc >> 7) * 2048;
            uint4* Wdst = (uint4*)Wt;
            for (int i = tid; i < 2048; i += 256) Wdst[i] = Wsrc[i];
        }
        __syncthreads();
        for (int k0 = 0; k0 < 128; k0 += 32) {
            short8 af0, af1;
            if (AMODE == 1) {
                af0 = cvt_frag(*(const float4*)(Af + rb0 + kc + k0),
                               *(const float4*)(Af + rb0 + kc + k0 + 4));
                af1 = cvt_frag(*(const float4*)(Af + rb1 + kc + k0),
                               *(const float4*)(Af + rb1 + kc + k0 + 4));
            } else {
                int kb4 = k0 + quad * 8;
                float4 A0 = *(const float4*)&As[kb4], A1 = *(const float4*)&As[kb4 + 4];
                float4 C0 = *(const float4*)&Cs[kb4], C1 = *(const float4*)&Cs[kb4 + 4];
                af0 = bn_frag(*(const short8*)(Ab + rb0 + k0), A0, A1, C0, C1);
                af1 = bn_frag(*(const short8*)(Ab + rb1 + k0), A0, A1, C0, C1);
            }
            if (!v0) af0 = (short8)(short)0;
            if (!v1) af1 = (short8)(short)0;
            const int kb = (k0 >> 3) + quad;
#pragma unroll
            for (int c = 0; c < 8; c++) {
                const int n = c * 16 + l16;
                short8 bf = *(const short8*)&Wt[n * 128 + (((kb + n) & 15) << 3)];
                acc[0][c] = __builtin_amdgcn_mfma_f32_16x16x32_bf16(af0, bf, acc[0][c], 0, 0, 0);
                acc[1][c] = __builtin_amdgcn_mfma_f32_16x16x32_bf16(af1, bf, acc[1][c], 0, 0, 0);
            }
        }
    }
#pragma unroll
    for (int g = 0; g < 2; g++) {
#pragma unroll
        for (int c = 0; c < 8; c++)
#pragma unroll
            for (int r = 0; r < 4; r++)
                tb[wave][quad * 4 + r][c * 16 + l16] = f2bf(acc[g][c][r]);
        asm volatile("s_waitcnt lgkmcnt(0)" ::: "memory");
#pragma unroll
        for (int j = 0; j < 4; j++) {
            int row_l = j * 4 + (lane >> 4);
            int row = rowt + g * 16 + row_l;
            if (row < M) {
                short8 vv = *(const short8*)&tb[wave][row_l][(lane & 15) * 8];
                *(short8*)(C + (size_t)row * 128 + (lane & 15) * 8) = vv;
            }
        }
        if (g == 0) asm volatile("s_waitcnt lgkmcnt(0)" ::: "memory");
    }
}

// ---------------- quarter-wave gather: 16 lanes/row, uint4 (8 bf16)/lane ----
// dst[r] = (1/cnt[r]) * sum src[members]; 4 rows per wave, 16 B/lane loads.
// cnt and col load concurrently (col read unconditionally; garbage lanes are
// never shfl-selected); the member loop always issues a full clamp-and-mask
// group of 4 (clamped lanes re-read the last member's line — TA dedups
// same-line lanes — and are masked to 0 before accumulation).
// STATS: per-lane 8-column raw moments -> LDS -> one 256-atomic flush/block.
// (fp8-E experiment REVERTED: 3-layer compounding of e4m3 noise broke the
// 0.241 absmax budget at 0.703. bf16 rows = 2 lines/member is the floor.)
template<int STATS>
__global__ __launch_bounds__(256) void gather_q(
    const u16* __restrict__ src, const int* __restrict__ cnt,
    const int* __restrict__ col, u16* __restrict__ dst,
    float* __restrict__ stat, float* __restrict__ zp,
    const uint2* __restrict__ ovf, const int* __restrict__ ovfCnt, int nrows)
{
    if (zp && blockIdx.x == 0) zp[threadIdx.x] = 0.0f;
    const int tid  = threadIdx.x;
    const int lane = tid & 63;
    const int ql   = lane & 15;       // lane within quarter
    const int qid  = tid >> 4;        // quarter id within block, 0..15
    const int bsel = lane & 48;       // shfl base for this quarter
    const u16* srcq = src + ql * 8;   // this lane's 8 columns
    float s1[8] = {0,0,0,0,0,0,0,0};
    float s2[8] = {0,0,0,0,0,0,0,0};

    for (int rr = blockIdx.x * 16; rr < nrows; rr += gridDim.x * 16) {
        int r = rr + qid;
        if (r < nrows) {
            int c = cnt[r];
            int m = col[(r << 4) + ql];      // issues concurrently with cnt
            int cc = (c > CAP) ? CAP : c;
            float a[8] = {0,0,0,0,0,0,0,0};
            int cl = cc - 1;
            for (int j = 0; j < cc; j += 4) {
                int i1 = (j + 1 > cl) ? cl : j + 1;
                int i2 = (j + 2 > cl) ? cl : j + 2;
                int i3 = (j + 3 > cl) ? cl : j + 3;
                int t0 = __shfl(m, bsel | j);
                int t1 = __shfl(m, bsel | i1);
                int t2 = __shfl(m, bsel | i2);
                int t3 = __shfl(m, bsel | i3);
                uint4 va = *(const uint4*)(srcq + (size_t)t0 * 128);
                uint4 vb = *(const uint4*)(srcq + (size_t)t1 * 128);
                uint4 vc = *(const uint4*)(srcq + (size_t)t2 * 128);
                uint4 vd = *(const uint4*)(srcq + (size_t)t3 * 128);
                if (j + 1 > cl) vb = make_uint4(0, 0, 0, 0);
                if (j + 2 > cl) vc = make_uint4(0, 0, 0, 0);
                if (j + 3 > cl) vd = make_uint4(0, 0, 0, 0);
                acc8_bf(a, va); acc8_bf(a, vb); acc8_bf(a, vc); acc8_bf(a, vd);
            }
            if (c > CAP) {                 // rare: scan overflow list
                int nov = *ovfCnt; if (nov > OVF_MAX) nov = OVF_MAX;
                for (int i4 = 0; i4 < nov; i4++) {
                    uint2 p = ovf[i4];
                    if ((int)p.x == r)
                        acc8_bf(a, *(const uint4*)(srcq + (size_t)p.y * 128));
                }
            }
            float w = (c > 0) ? 1.0f / (float)c : 0.0f;
#pragma unroll
            for (int k = 0; k < 8; k++) a[k] *= w;
            uint4 o;
            o.x = (unsigned)f2bf(a[0]) | ((unsigned)f2bf(a[1]) << 16);
            o.y = (unsigned)f2bf(a[2]) | ((unsigned)f2bf(a[3]) << 16);
            o.z = (unsigned)f2bf(a[4]) | ((unsigned)f2bf(a[5]) << 16);
            o.w = (unsigned)f2bf(a[6]) | ((unsigned)f2bf(a[7]) << 16);
            *(uint4*)(dst + (size_t)r * 128 + ql * 8) = o;
            if (STATS) {
#pragma unroll
                for (int k = 0; k < 8; k++) { s1[k] += a[k]; s2[k] += a[k] * a[k]; }
            }
        }
    }
    if (STATS) {
        __shared__ float redS[16][128];
        __shared__ float redQ[16][128];
#pragma unroll
        for (int k = 0; k < 8; k++) {
            redS[qid][ql * 8 + k] = s1[k];
            redQ[qid][ql * 8 + k] = s2[k];
        }
        __syncthreads();
        int t = tid & 127;
        float accv = 0.0f;
        if (tid < 128) {
#pragma unroll
            for (int q = 0; q < 16; q++) accv += redS[q][t];
            atomAddF(&stat[t], accv);
        } else {
#pragma unroll
            for (int q = 0; q < 16; q++) accv += redQ[q][t];
            atomAddF(&stat[128 + t], accv);
        }
    }
}

// ---------------- MFMA classifier with fused BN on the A-path ---------------
__global__ __launch_bounds__(256) void classifier_mfma(
    const u16* __restrict__ Z, const float* __restrict__ Wc1,
    const float* __restrict__ bc1, const float* __restrict__ Wc2,
    const float* __restrict__ bc2, float* __restrict__ out, int M,
    const float* __restrict__ gsum, const float* __restrict__ gsq,
    const float* __restrict__ gam, const float* __restrict__ bet, float invM)
{
    __shared__ __attribute__((aligned(16))) u16 W1t[64 * 128];   // 16 KB
    __shared__ __attribute__((aligned(16))) u16 W2t[16 * 64];    // 2 KB
    __shared__ __attribute__((aligned(16))) u16 hs[128][72];     // 18.4 KB
    __shared__ __attribute__((aligned(16))) float As[128];
    __shared__ __attribute__((aligned(16))) float Cs[128];
    const int tid = threadIdx.x;
    if (tid < 128) {
        float s1 = gsum[tid] * invM;
        float var = gsq[tid] * invM - s1 * s1;
        if (var < 0.0f) var = 0.0f;
        float sc = gam[tid] * rsqrtf(var + 1e-5f);
        As[tid] = sc;
        Cs[tid] = bet[tid] - s1 * sc;
    }
    for (int i = tid; i < 64 * 128; i += 256) {   // i = k*64 + n
        int k = i >> 6, n = i & 63;
        int kb = k >> 3, kin = k & 7;
        W1t[n * 128 + (((kb + n) & 15) << 3) + kin] = f2bf(Wc1[i]);
    }
    for (int i = tid; i < 16 * 64; i += 256) {    // i = k*16 + n
        int k = i >> 4, n = i & 15;
        W2t[n * 64 + k] = (n < 10) ? f2bf(Wc2[k * 10 + n]) : (u16)0;
    }
    __syncthreads();

    const int wave = tid >> 6, lane = tid & 63;
    const int l16 = lane & 15, quad = lane >> 4;
    const int rowt = blockIdx.x * 128 + wave * 32;
    const int r0 = rowt + l16, r1 = rowt + 16 + l16;
    const bool v0 = r0 < M, v1 = r1 < M;
    const u16* a0p = Z + (size_t)(v0 ? r0 : 0) * 128 + quad * 8;
    const u16* a1p = Z + (size_t)(v1 ? r1 : 0) * 128 + quad * 8;

    float4v acc[2][4];
#pragma unroll
    for (int g = 0; g < 2; g++)
#pragma unroll
        for (int c = 0; c < 4; c++) acc[g][c] = (float4v)0.0f;

#pragma unroll
    for (int k0 = 0; k0 < 128; k0 += 32) {
        int kb4 = k0 + quad * 8;
        float4 A0 = *(const float4*)&As[kb4], A1 = *(const float4*)&As[kb4 + 4];
        float4 C0 = *(const float4*)&Cs[kb4], C1 = *(const float4*)&Cs[kb4 + 4];
        short8 af0 = bn_frag(*(const short8*)(a0p + k0), A0, A1, C0, C1);
        short8 af1 = bn_frag(*(const short8*)(a1p + k0), A0, A1, C0, C1);
        if (!v0) af0 = (short8)(short)0;
        if (!v1) af1 = (short8)(short)0;
        const int kb = (k0 >> 3) + quad;
#pragma unroll
        for (int c = 0; c < 4; c++) {
            const int n = c * 16 + l16;
            short8 bf = *(const short8*)&W1t[n * 128 + (((kb + n) & 15) << 3)];
            acc[0][c] = __builtin_amdgcn_mfma_f32_16x16x32_bf16(af0, bf, acc[0][c], 0, 0, 0);
            acc[1][c] = __builtin_amdgcn_mfma_f32_16x16x32_bf16(af1, bf, acc[1][c], 0, 0, 0);
        }
    }
#pragma unroll
    for (int g = 0; g < 2; g++)
#pragma unroll
        for (int c = 0; c < 4; c++) {
            float b = bc1[c * 16 + l16];
#pragma unroll
            for (int r = 0; r < 4; r++)
                hs[wave * 32 + g * 16 + quad * 4 + r][c * 16 + l16] =
                    f2bf(fmaxf(acc[g][c][r] + b, 0.0f));
        }
    asm volatile("s_waitcnt lgkmcnt(0)" ::: "memory");

    float4v a2[2];
    a2[0] = (float4v)0.0f; a2[1] = (float4v)0.0f;
#pragma unroll
    for (int k0 = 0; k0 < 64; k0 += 32) {
        short8 bf = *(const short8*)&W2t[l16 * 64 + k0 + quad * 8];
#pragma unroll
        for (int g = 0; g < 2; g++) {
            short8 af = *(const short8*)&hs[wave * 32 + g * 16 + l16][k0 + quad * 8];
            a2[g] = __builtin_amdgcn_mfma_f32_16x16x32_bf16(af, bf, a2[g], 0, 0, 0);
        }
    }
    if (l16 < 10) {
        float b2 = bc2[l16];
#pragma unroll
        for (int g = 0; g < 2; g++)
#pragma unroll
            for (int r = 0; r < 4; r++) {
                int row = rowt + g * 16 + quad * 4 + r;
                if (row < M) out[(size_t)row * 10 + l16] = a2[g][r] + b2;
            }
    }
}

// ---------------- launch ----------------------------------------------------
extern "C" void kernel_launch(void* const* d_in, const int* in_sizes, int n_in,
                              void* d_out, int out_size, void* d_ws, size_t ws_size,
                              hipStream_t stream)
{
    const int M   = N_NODES;
    const int NE  = N_EDGES;
    const int nnz = NNZ_C;

    const float* x   = (const float*)d_in[0];
    const int*  nidx = (const int*)d_in[1];
    const int*  eidx = nidx + nnz;
    const float* W1  = (const float*)d_in[2];
    const float* W2  = (const float*)d_in[4];
    const float* W3  = (const float*)d_in[6];
    const float* g1  = (const float*)d_in[8];
    const float* bt1 = (const float*)d_in[9];
    const float* g2  = (const float*)d_in[10];
    const float* bt2 = (const float*)d_in[11];
    const float* g3  = (const float*)d_in[12];
    const float* bt3 = (const float*)d_in[13];
    const float* Wc1 = (const float*)d_in[14];
    const float* bc1 = (const float*)d_in[15];
    const float* Wc2 = (const float*)d_in[16];
    const float* bc2 = (const float*)d_in[17];
    float* out = (float*)d_out;

    // ---- workspace carve-up ----
    const size_t SZH = (size_t)M * 128 * sizeof(u16);   // 25.6 MB
    char* ws = (char*)d_ws;
    u16* Y = (u16*)(ws);                     // GEMM output (bf16)
    u16* E = (u16*)(ws + SZH);               // edge features (bf16)
    u16* Z = (u16*)(ws + 2 * SZH);           // node agg, pre-BN (bf16)
    int* ib = (int*)(ws + 3 * SZH);
    int*   cb      = ib;                     // edge sizes [100000]
    int*   cd      = ib + 100000;            // node degrees
    int*   colB    = ib + 200016;            // 64-B aligned; [100000*16]
    int*   colD    = ib + 200016 + NE * CAP;
    uint2* ovfB    = (uint2*)(ib + 200016 + (NE + M) * CAP);
    uint2* ovfD    = ovfB + OVF_MAX;
    float* fb = (float*)(ovfD + OVF_MAX);
    float* gsum = fb;                        // [128]; gsq contiguous after
    u16* wbuf = (u16*)(fb + 256);
    u16* W1b = wbuf;                         // 2 chunks x 16384 (swizzled)
    u16* W2b = wbuf + 32768;                 // 1 chunk
    u16* W3b = wbuf + 49152;                 // 1 chunk
    int* gq  = (int*)(wbuf + 65536);         // [2*NBIN cursors][2 ovf counters]
    int* ovfCntB = gq + 2 * NBIN;
    int* ovfCntD = gq + 2 * NBIN + 1;
    // staging lives in E/Z regions (dead until after gemm0's pass B)
    uint2* stageB = (uint2*)E;               // 196*4096*8 = 6.42 MB
    uint2* stageD = (uint2*)Z;

    const int ntiles = (M + 127) / 128;
    const float invM = 1.0f / (float)M;

    // zero bin cursors + overflow counters (tiny)
    hipMemsetAsync(gq, 0, (2 * NBIN + 2) * sizeof(int), stream);

    // ---- weight convert + fill pass A (role-split grid, sides parallel) ----
    convert_binA<<<2 * PA_BLOCKS + 256, 256, 0, stream>>>(
        W1, W2, W3, W1b, W2b, W3b, nidx, eidx, stageB, stageD, gq, nnz);

    const float* gin[3]  = { g1, g2, g3 };
    const float* btin[3] = { bt1, bt2, bt3 };
    const u16*   Wbf[3]  = { W1b, W2b, W3b };

    for (int L = 0; L < 3; L++) {
        if (L == 0)
            // GEMM0 sharing its grid with 2*NBIN fill pass-B blocks
            gemm_mfma<256, 1, 1><<<2 * NBIN + ntiles, 256, 0, stream>>>(
                x, Wbf[0], Y, M, nullptr, nullptr, nullptr, nullptr, 0.0f,
                stageB, stageD, gq, cb, cd, colB, colD, ovfB, ovfD,
                ovfCntB, ovfCntD);
        else
            gemm_mfma<128, 2, 0><<<ntiles, 256, 0, stream>>>(
                Z, Wbf[L], Y, M, gsum, gsum + 128, gin[L - 1], btin[L - 1], invM,
                nullptr, nullptr, nullptr, nullptr, nullptr, nullptr, nullptr,
                nullptr, nullptr, nullptr, nullptr);
        // edge aggregation; block 0 zeros gsum||gsq for the node pass
        gather_q<0><<<(NE + 15) / 16, 256, 0, stream>>>(
            Y, cb, colB, E, nullptr, gsum, ovfB, ovfCntB, NE);
        // node aggregation with fused raw-moment stats (2048 blocks = 8/CU)
        gather_q<1><<<2048, 256, 0, stream>>>(
            E, cd, colD, Z, gsum, nullptr, ovfD, ovfCntD, M);
    }

    classifier_mfma<<<ntiles, 256, 0, stream>>>(
        Z, Wc1, bc1, Wc2, bc2, out, M, gsum, gsum + 128, gin[2], btin[2], invM);
}